// Round 6
// baseline (657.982 us; speedup 1.0000x reference)
//
#include <hip/hip_runtime.h>

typedef unsigned short ushort_t;
typedef unsigned int uint32;

#define N_NODES 10000
#define N_EDGES 160000
#define ET (N_NODES + N_EDGES)   /* 170000 edges incl self-loops */
#define HT 1024                  /* heads * hid */
#define HEADS 8
#define NEG 0.2f
#define NB 512                   /* blocks in cooperative-style kernels (2/CU, co-resident) */

/* ---- ws layout (bytes, 256-aligned) ---- */
#define O_DONE     0             /* 512 ints, grid-barrier slots for k_front */
#define O_DONE2    2048          /* 512 ints, for k_tail */
#define O_BSUM     4096          /* 512 ints, scan block sums */
#define O_COUNTS   6144
#define O_OFFS     (O_COUNTS + 40192)
#define O_CURS     (O_OFFS + 40192)
#define O_SSORT    (O_CURS + 40192)
#define O_ALS      (O_SSORT + 680192)
#define O_ALD      (O_ALS + 320000)
#define O_AL3S     (O_ALD + 320000)
#define O_AL3D     (O_AL3S + 40192)
#define O_H3       (O_AL3D + 40192)
#define O_WVEC     (O_H3 + 160000)      /* 6 x 1024 floats: as1,ad1,b1,as2,ad2,b2 */
#define O_W3F      (O_WVEC + 24576)     /* 4096 floats */
#define O_S3F      (O_W3F + 16384)      /* as3 @0, ad3 @+16 floats, b3 @+32 floats */
#define O_W2T      (O_S3F + 768)        /* bf16 [1024,1024] transposed */
#define O_BUFA     (O_W2T + 2097152)
#define O_BUFB     (O_BUFA + 20709376)

__device__ __forceinline__ float bf2f(ushort_t u){ return __uint_as_float(((uint32)u) << 16); }
__device__ __forceinline__ ushort_t f2bf(float f){
    uint32 x = __float_as_uint(f);
    return (ushort_t)((x + 0x7fffu + ((x >> 16) & 1u)) >> 16);
}
__device__ __forceinline__ void unpack2(uint32 u, float& lo, float& hi){
    lo = __uint_as_float(u << 16);
    hi = __uint_as_float(u & 0xffff0000u);
}

typedef __bf16 bf16x8 __attribute__((ext_vector_type(8)));
typedef float  f32x4  __attribute__((ext_vector_type(4)));

typedef const __attribute__((address_space(1))) uint32* gas1_u32;
typedef       __attribute__((address_space(3))) uint32* las3_u32;

__device__ __forceinline__ void gload_lds16(const void* g, void* l){
    __builtin_amdgcn_global_load_lds((gas1_u32)g, (las3_u32)l, 16, 0, 0);
}

/* dtype probes: bf16 low-element exponent concentrates near 127; fp32 low 16
   bits are uniform mantissa bits. */
__device__ __forceinline__ int probe_f32(const uint32* __restrict__ w){
    int cnt = 0;
    for (int i = 0; i < 256; i++){
        uint32 e = (w[i] >> 7) & 0xffu;
        cnt += (e >= 64u && e <= 160u) ? 1 : 0;
    }
    return (cnt > 200) ? 0 : 1;
}
__device__ __forceinline__ int probe_edge64(const int* __restrict__ ei){
    int nz = 0;
    for (int i = 0; i < 128; i++) nz |= ei[2*i + 1];
    return (nz == 0) ? 1 : 0;
}

__device__ __forceinline__ float cvt1(const void* p, int i, int f32){
    return f32 ? ((const float*)p)[i] : bf2f(((const ushort_t*)p)[i]);
}

/* poison-tolerant grid barrier: per-block slot, monotone phase values (>=1);
   ws poison 0xAAAAAAAA is negative as int, so slots read "not arrived" until
   written. Device-scope release/acquire per G16. All NB blocks co-resident. */
__device__ __forceinline__ void gbar(int* done, int phase){
    __syncthreads();
    if (threadIdx.x == 0)
        __hip_atomic_store(&done[blockIdx.x], phase, __ATOMIC_RELEASE, __HIP_MEMORY_SCOPE_AGENT);
    #pragma unroll 1
    for (int s = threadIdx.x; s < NB; s += 256){
        while (__hip_atomic_load(&done[s], __ATOMIC_ACQUIRE, __HIP_MEMORY_SCOPE_AGENT) < phase){}
    }
    __syncthreads();
}

struct FrontArgs {
    const void* vsrc[6];   /* as1,ad1,b1,as2,ad2,b2 */
    const void* w3src;
    const void* s3src[3];  /* as3,ad3,b3 */
};

/* ---------------- k_front: setup + edge CSR + layer-1 GEMM/dots, one dispatch ---------------- */
__global__ __launch_bounds__(256) void k_front(
        const void* __restrict__ x, const void* __restrict__ ei,
        const void* __restrict__ W1, const void* __restrict__ W2, FrontArgs fa,
        float* __restrict__ wvecF, float* __restrict__ W3F, float* __restrict__ s3F,
        ushort_t* __restrict__ W2T,
        int* __restrict__ counts, int* __restrict__ offs, int* __restrict__ cursors,
        int* __restrict__ ssort, int* __restrict__ bsum, int* __restrict__ done,
        ushort_t* __restrict__ h1, float* __restrict__ alS, float* __restrict__ alD){
    __shared__ float w1s[14 * HT];      /* 56 KB; aliased as transpose tile in P0 */
    __shared__ int sf32, se64;
    int tid = threadIdx.x, bid = blockIdx.x;
    int g = bid * 256 + tid;

    if (tid == 0) sf32 = probe_f32((const uint32*)W1);
    if (tid == 1) se64 = probe_edge64((const int*)ei);
    __syncthreads();
    int f32 = sf32, e64 = se64;

    /* ---- P0: counts zero, small conversions, W2 transpose ---- */
    if (g < N_NODES) counts[g] = 0;
    if (g < 6144){
        wvecF[g] = cvt1(fa.vsrc[g >> 10], g & 1023, f32);
    } else if (g < 10240){
        int off = g - 6144;
        W3F[off] = cvt1(fa.w3src, off, f32);
    } else if (g < 10252){
        int off = g - 10240;
        int a = off >> 2, j = off & 3;
        s3F[a * 16 + j] = cvt1(fa.s3src[a], j, f32);
    }
    {
        ushort_t (*tile)[33] = (ushort_t (*)[33])w1s;
        int cx = tid & 31, ry = (tid >> 5) * 4;
        #pragma unroll 1
        for (int tt = 0; tt < 2; tt++){
            int t = bid * 2 + tt;
            int bx = t & 31, by = t >> 5;
            __syncthreads();
            #pragma unroll
            for (int r = 0; r < 4; r++){
                size_t idx = (size_t)(by*32 + ry + r)*1024 + bx*32 + cx;
                tile[ry + r][cx] = f32 ? f2bf(((const float*)W2)[idx]) : ((const ushort_t*)W2)[idx];
            }
            __syncthreads();
            #pragma unroll
            for (int r = 0; r < 4; r++)
                W2T[(size_t)(bx*32 + ry + r)*1024 + by*32 + cx] = tile[cx][ry + r];
        }
    }
    gbar(done, 1);

    /* ---- P1: histogram of dst ---- */
    #pragma unroll 1
    for (int i = g; i < ET; i += NB * 256){
        int d;
        if (i < N_EDGES){
            d = e64 ? (int)((const long long*)ei)[N_EDGES + i] : ((const int*)ei)[N_EDGES + i];
        } else d = i - N_EDGES;
        atomicAdd(&counts[d], 1);
    }
    gbar(done, 2);

    /* ---- P2a: per-chunk sums (chunk = 20 nodes) ---- */
    if (tid < 64){
        int idx = bid * 20 + tid;
        int v = (tid < 20 && idx < N_NODES) ? counts[idx] : 0;
        #pragma unroll
        for (int o = 32; o; o >>= 1) v += __shfl_xor(v, o, 64);
        if (tid == 0) bsum[bid] = v;
    }
    gbar(done, 3);

    /* ---- P2b: block 0 scans the 512 chunk sums (exclusive, in place) ---- */
    if (bid == 0 && tid < 64){
        int l = tid;
        int v[8];
        #pragma unroll
        for (int k = 0; k < 8; k++) v[k] = bsum[l*8 + k];
        int tot = 0;
        #pragma unroll
        for (int k = 0; k < 8; k++){ int t = v[k]; v[k] = tot; tot += t; }
        int inc = tot;
        #pragma unroll
        for (int d = 1; d < 64; d <<= 1){
            int t = __shfl_up(inc, d, 64);
            if (l >= d) inc += t;
        }
        int excl = inc - tot;
        #pragma unroll
        for (int k = 0; k < 8; k++) bsum[l*8 + k] = excl + v[k];
    }
    gbar(done, 4);

    /* ---- P2c: per-chunk exclusive scan -> offs, cursors ---- */
    if (tid < 64){
        int base = bsum[bid];
        int idx = bid * 20 + tid;
        int v = (tid < 20 && idx < N_NODES) ? counts[idx] : 0;
        int inc = v;
        #pragma unroll
        for (int d = 1; d < 64; d <<= 1){
            int t = __shfl_up(inc, d, 64);
            if (tid >= d) inc += t;
        }
        int excl = base + inc - v;
        if (tid < 20 && idx < N_NODES){ offs[idx] = excl; cursors[idx] = excl; }
    }
    if (g == 0) offs[N_NODES] = ET;
    gbar(done, 5);

    /* ---- P3: scatter src by dst ---- */
    #pragma unroll 1
    for (int i = g; i < ET; i += NB * 256){
        int s, d;
        if (i < N_EDGES){
            if (e64){
                s = (int)((const long long*)ei)[i];
                d = (int)((const long long*)ei)[N_EDGES + i];
            } else {
                s = ((const int*)ei)[i];
                d = ((const int*)ei)[N_EDGES + i];
            }
        } else { s = i - N_EDGES; d = s; }
        int pos = atomicAdd(&cursors[d], 1);
        ssort[pos] = s;
    }

    /* ---- P4: layer-1 GEMM + attention dots (W1 in LDS) ---- */
    __syncthreads();
    if (f32){
        for (int i = tid * 4; i < 14 * HT; i += 1024)
            *(float4*)(w1s + i) = *(const float4*)((const float*)W1 + i);
    } else {
        for (int i = tid * 4; i < 14 * HT; i += 1024){
            uint2 u = *(const uint2*)((const ushort_t*)W1 + i);
            unpack2(u.x, w1s[i], w1s[i+1]);
            unpack2(u.y, w1s[i+2], w1s[i+3]);
        }
    }
    __syncthreads();
    int c0 = tid * 4;
    float4 sv = *(const float4*)(wvecF + c0);
    float4 dv = *(const float4*)(wvecF + 1024 + c0);
    int head = tid >> 5, l32 = tid & 31;
    #pragma unroll 1
    for (int n = bid; n < N_NODES; n += NB){
        float a0=0.f, a1=0.f, a2=0.f, a3=0.f;
        #pragma unroll
        for (int k = 0; k < 14; k++){
            float xv = f32 ? ((const float*)x)[n*14 + k] : bf2f(((const ushort_t*)x)[n*14 + k]);
            float4 w = *(const float4*)(w1s + k*HT + c0);
            a0 += xv*w.x; a1 += xv*w.y; a2 += xv*w.z; a3 += xv*w.w;
        }
        uint2 o;
        o.x = (uint32)f2bf(a0) | ((uint32)f2bf(a1) << 16);
        o.y = (uint32)f2bf(a2) | ((uint32)f2bf(a3) << 16);
        *(uint2*)(h1 + (size_t)n*HT + c0) = o;
        float h0,h1v,h2,h3v;
        unpack2(o.x, h0, h1v); unpack2(o.y, h2, h3v);
        float s = h0*sv.x + h1v*sv.y + h2*sv.z + h3v*sv.w;
        float d = h0*dv.x + h1v*dv.y + h2*dv.z + h3v*dv.w;
        #pragma unroll
        for (int of = 16; of; of >>= 1){ s += __shfl_xor(s, of, 32); d += __shfl_xor(d, of, 32); }
        if (l32 == 0){ alS[n*HEADS + head] = s; alD[n*HEADS + head] = d; }
    }
}

/* ---------------- fused segment-softmax + aggregate + bias + relu ----------------
   Barrier-free: 2 nodes/block, 2 waves/node; lane owns 8 channels.
   Phase-2 unrolled x4 for gather-latency hiding. */
__global__ __launch_bounds__(256) void k_gat_agg(const ushort_t* __restrict__ H, const float* __restrict__ alS,
                                                 const float* __restrict__ alD, const int* __restrict__ offs,
                                                 const int* __restrict__ srcs, const float* __restrict__ bias,
                                                 ushort_t* __restrict__ out){
    int tid = threadIdx.x;
    int wv = tid >> 6, lane = tid & 63;
    int n = blockIdx.x * 2 + (wv >> 1);
    int half = wv & 1;
    int beg = offs[n], end = offs[n+1];
    int head = half*4 + (lane >> 4);
    int slot = lane & 15;
    float ad = alD[n*HEADS + head];

    float m = -1e30f, z = 0.f;
    for (int c = beg; c < end; c += 64){
        int cn = min(64, end - c);
        int sreg = (lane < cn) ? srcs[c + lane] : 0;
        for (int p = slot; p < cn; p += 16){
            int s = __shfl(sreg, p, 64);
            float v = alS[s*HEADS + head] + ad;
            v = v > 0.f ? v : NEG*v;
            if (v > m){ z = z*__expf(m - v) + 1.f; m = v; }
            else z += __expf(v - m);
        }
    }
    #pragma unroll
    for (int o = 1; o < 16; o <<= 1){
        float m2 = __shfl_xor(m, o, 64);
        float z2 = __shfl_xor(z, o, 64);
        float nm = fmaxf(m, m2);
        z = z*__expf(m - nm) + z2*__expf(m2 - nm);
        m = nm;
    }
    float inv = 1.f / (z + 1e-16f);

    int ch0 = half*512 + lane*8;
    const ushort_t* Hc = H + ch0;
    float c0=0.f,c1=0.f,c2=0.f,c3=0.f,c4=0.f,c5=0.f,c6=0.f,c7=0.f;
    for (int c = beg; c < end; c += 64){
        int cn = min(64, end - c);
        int sreg = (lane < cn) ? srcs[c + lane] : 0;
        int j = 0;
        for (; j + 4 <= cn; j += 4){
            int s0 = __shfl(sreg, j, 64);
            int s1 = __shfl(sreg, j+1, 64);
            int s2 = __shfl(sreg, j+2, 64);
            int s3 = __shfl(sreg, j+3, 64);
            float e0 = alS[s0*HEADS + head];
            float e1 = alS[s1*HEADS + head];
            float e2 = alS[s2*HEADS + head];
            float e3 = alS[s3*HEADS + head];
            uint4 u0 = *(const uint4*)(Hc + (size_t)s0*HT);
            uint4 u1 = *(const uint4*)(Hc + (size_t)s1*HT);
            uint4 u2 = *(const uint4*)(Hc + (size_t)s2*HT);
            uint4 u3 = *(const uint4*)(Hc + (size_t)s3*HT);
            float v0 = e0 + ad; v0 = v0 > 0.f ? v0 : NEG*v0;
            float v1 = e1 + ad; v1 = v1 > 0.f ? v1 : NEG*v1;
            float v2 = e2 + ad; v2 = v2 > 0.f ? v2 : NEG*v2;
            float v3 = e3 + ad; v3 = v3 > 0.f ? v3 : NEG*v3;
            float w0 = __expf(v0 - m) * inv;
            float w1 = __expf(v1 - m) * inv;
            float w2 = __expf(v2 - m) * inv;
            float w3 = __expf(v3 - m) * inv;
            float f0,f1,f2,f3,f4,f5,f6,f7;
            unpack2(u0.x,f0,f1); unpack2(u0.y,f2,f3); unpack2(u0.z,f4,f5); unpack2(u0.w,f6,f7);
            c0+=w0*f0; c1+=w0*f1; c2+=w0*f2; c3+=w0*f3;
            c4+=w0*f4; c5+=w0*f5; c6+=w0*f6; c7+=w0*f7;
            unpack2(u1.x,f0,f1); unpack2(u1.y,f2,f3); unpack2(u1.z,f4,f5); unpack2(u1.w,f6,f7);
            c0+=w1*f0; c1+=w1*f1; c2+=w1*f2; c3+=w1*f3;
            c4+=w1*f4; c5+=w1*f5; c6+=w1*f6; c7+=w1*f7;
            unpack2(u2.x,f0,f1); unpack2(u2.y,f2,f3); unpack2(u2.z,f4,f5); unpack2(u2.w,f6,f7);
            c0+=w2*f0; c1+=w2*f1; c2+=w2*f2; c3+=w2*f3;
            c4+=w2*f4; c5+=w2*f5; c6+=w2*f6; c7+=w2*f7;
            unpack2(u3.x,f0,f1); unpack2(u3.y,f2,f3); unpack2(u3.z,f4,f5); unpack2(u3.w,f6,f7);
            c0+=w3*f0; c1+=w3*f1; c2+=w3*f2; c3+=w3*f3;
            c4+=w3*f4; c5+=w3*f5; c6+=w3*f6; c7+=w3*f7;
        }
        for (; j < cn; j++){
            int s0 = __shfl(sreg, j, 64);
            uint4 u0 = *(const uint4*)(Hc + (size_t)s0*HT);
            float v0 = alS[s0*HEADS + head] + ad;
            v0 = v0 > 0.f ? v0 : NEG*v0;
            float w0 = __expf(v0 - m) * inv;
            float f0,f1,f2,f3,f4,f5,f6,f7;
            unpack2(u0.x,f0,f1); unpack2(u0.y,f2,f3); unpack2(u0.z,f4,f5); unpack2(u0.w,f6,f7);
            c0+=w0*f0; c1+=w0*f1; c2+=w0*f2; c3+=w0*f3;
            c4+=w0*f4; c5+=w0*f5; c6+=w0*f6; c7+=w0*f7;
        }
    }
    float4 b0 = *(const float4*)(bias + ch0);
    float4 b1 = *(const float4*)(bias + ch0 + 4);
    c0 = fmaxf(c0+b0.x, 0.f); c1 = fmaxf(c1+b0.y, 0.f);
    c2 = fmaxf(c2+b0.z, 0.f); c3 = fmaxf(c3+b0.w, 0.f);
    c4 = fmaxf(c4+b1.x, 0.f); c5 = fmaxf(c5+b1.y, 0.f);
    c6 = fmaxf(c6+b1.z, 0.f); c7 = fmaxf(c7+b1.w, 0.f);
    uint4 o;
    o.x = (uint32)f2bf(c0) | ((uint32)f2bf(c1) << 16);
    o.y = (uint32)f2bf(c2) | ((uint32)f2bf(c3) << 16);
    o.z = (uint32)f2bf(c4) | ((uint32)f2bf(c5) << 16);
    o.w = (uint32)f2bf(c6) | ((uint32)f2bf(c7) << 16);
    *(uint4*)(out + (size_t)n*HT + ch0) = o;
}

/* ---------------- layer-2 GEMM: bf16 MFMA, double-buffered, fused dots ----------------
   Statically-disjoint LDS buffers + 2x-unrolled K-loop so the compiler can keep
   the next-tile global_load_lds in flight across the current tile's compute.
   One __syncthreads per k-step (its vmcnt drain is the prefetch wait).
   XCD-swizzled grid + LDS XOR swizzle (conflict-free fragment reads). */
#define G2_STAGE(kk, LA, LB) { \
    _Pragma("unroll") \
    for (int it = 0; it < 2; ++it){ \
        int s_ = tid + it*256; \
        int r_ = s_ >> 2, p_ = s_ & 3; \
        int q_ = p_ ^ ((r_ >> 1) & 3); \
        gload_lds16(A  + (size_t)(rowA0 + r_)*1024 + (kk) + q_*8, LA + s_*8); \
        gload_lds16(BT + (size_t)(rowB0 + r_)*1024 + (kk) + q_*8, LB + s_*8); \
    } }

#define G2_COMP(LA, LB) { \
    bf16x8 af[4], bfr[4]; \
    _Pragma("unroll") \
    for (int mt = 0; mt < 4; mt++) af[mt]  = *(const bf16x8*)(LA + (wm + mt*16 + lm)*32 + kp); \
    _Pragma("unroll") \
    for (int nt = 0; nt < 4; nt++) bfr[nt] = *(const bf16x8*)(LB + (wn + nt*16 + lm)*32 + kp); \
    _Pragma("unroll") \
    for (int mt = 0; mt < 4; mt++) \
        _Pragma("unroll") \
        for (int nt = 0; nt < 4; nt++) \
            acc[mt][nt] = __builtin_amdgcn_mfma_f32_16x16x32_bf16(af[mt], bfr[nt], acc[mt][nt], 0, 0, 0); \
    }

__global__ __launch_bounds__(256) void k_gemm2(const ushort_t* __restrict__ A, const ushort_t* __restrict__ BT,
                                               ushort_t* __restrict__ C,
                                               const float* __restrict__ aS, const float* __restrict__ aD,
                                               float* __restrict__ alS, float* __restrict__ alD){
    __shared__ ushort_t lA0[4096], lA1[4096];
    __shared__ ushort_t lB0[4096], lB1[4096];
    __shared__ float reds[2][64][2];
    int L = blockIdx.x;
    int xcd = L & 7;
    int wi  = L >> 3;
    int bm  = xcd * 10 + (wi >> 3);
    int bn  = wi & 7;
    if (bm >= 79) return;
    int tid = threadIdx.x;
    int lane = tid & 63;
    int wave = tid >> 6;
    int wm = (wave & 1) * 64, wn = (wave >> 1) * 64;
    int lm = lane & 15, kg = lane >> 4;
    int sw = (lm >> 1) & 3;
    int kp = (kg ^ sw) * 8;
    f32x4 acc[4][4];
    #pragma unroll
    for (int i = 0; i < 4; i++)
        #pragma unroll
        for (int j = 0; j < 4; j++) acc[i][j] = (f32x4)0.0f;

    int rowA0 = bm * 128, rowB0 = bn * 128;

    G2_STAGE(0, lA0, lB0);
    __syncthreads();
    #pragma unroll 1
    for (int k0 = 0; k0 < 1024; k0 += 64){
        if (k0 + 32 < 1024) G2_STAGE(k0 + 32, lA1, lB1);
        G2_COMP(lA0, lB0);
        __syncthreads();
        if (k0 + 64 < 1024) G2_STAGE(k0 + 64, lA0, lB0);
        G2_COMP(lA1, lB1);
        __syncthreads();
    }

    #pragma unroll
    for (int mt = 0; mt < 4; mt++){
        int row_base = bm*128 + wm + mt*16 + kg*4;
        #pragma unroll
        for (int nt = 0; nt < 4; nt++){
            int col = bn*128 + wn + nt*16 + lm;
            #pragma unroll
            for (int r = 0; r < 4; r++){
                int row = row_base + r;
                if (row < N_NODES) C[(size_t)row*HT + col] = f2bf(acc[mt][nt][r]);
            }
        }
    }
    /* fused attention-dot epilogue for head bn */
    float as_l[4], ad_l[4];
    #pragma unroll
    for (int nt = 0; nt < 4; nt++){
        as_l[nt] = aS[bn*128 + wn + nt*16 + lm];
        ad_l[nt] = aD[bn*128 + wn + nt*16 + lm];
    }
    float psA[4][4], pdA[4][4];
    #pragma unroll
    for (int mt = 0; mt < 4; mt++){
        #pragma unroll
        for (int r = 0; r < 4; r++){
            float ps = acc[mt][0][r]*as_l[0] + acc[mt][1][r]*as_l[1]
                     + acc[mt][2][r]*as_l[2] + acc[mt][3][r]*as_l[3];
            float pd = acc[mt][0][r]*ad_l[0] + acc[mt][1][r]*ad_l[1]
                     + acc[mt][2][r]*ad_l[2] + acc[mt][3][r]*ad_l[3];
            #pragma unroll
            for (int o = 1; o < 16; o <<= 1){ ps += __shfl_xor(ps, o, 64); pd += __shfl_xor(pd, o, 64); }
            psA[mt][r] = ps; pdA[mt][r] = pd;
            if (wn == 64 && lm == 0){
                int rl = mt*16 + kg*4 + r;
                reds[wm >> 6][rl][0] = ps;
                reds[wm >> 6][rl][1] = pd;
            }
        }
    }
    __syncthreads();
    if (wn == 0 && lm == 0){
        #pragma unroll
        for (int mt = 0; mt < 4; mt++){
            #pragma unroll
            for (int r = 0; r < 4; r++){
                int rl = mt*16 + kg*4 + r;
                int row = bm*128 + wm + rl;
                if (row < N_NODES){
                    alS[row*HEADS + bn] = psA[mt][r] + reds[wm >> 6][rl][0];
                    alD[row*HEADS + bn] = pdA[mt][r] + reds[wm >> 6][rl][1];
                }
            }
        }
    }
}

/* ---------------- k_tail: layer-3 GEMM + grid-bar + aggregate -> output ---------------- */
__global__ __launch_bounds__(256) void k_tail(const ushort_t* __restrict__ A, const float* __restrict__ W3F,
                                              const float* __restrict__ s3F, const int* __restrict__ offs,
                                              const int* __restrict__ ssort, const uint32* __restrict__ w1raw,
                                              float* __restrict__ h3, float* __restrict__ al3s,
                                              float* __restrict__ al3d, int* __restrict__ done2,
                                              void* __restrict__ out){
    int tid = threadIdx.x, bid = blockIdx.x;
    int lane = tid & 63, wave = tid >> 6;
    __shared__ int sf32;
    if (tid == 0) sf32 = probe_f32(w1raw);
    __syncthreads();
    int f32 = sf32;

    /* phase 1: gemm3, wave-per-node, W3 in registers */
    float4 w3r[16];
    #pragma unroll
    for (int j = 0; j < 16; j++) w3r[j] = ((const float4*)W3F)[lane*16 + j];
    #pragma unroll 1
    for (int n = bid*4 + wave; n < N_NODES; n += NB*4){
        const uint4* ap = (const uint4*)(A + (size_t)n*HT + lane*16);
        uint4 u0 = ap[0], u1 = ap[1];
        uint32 uu[8] = {u0.x,u0.y,u0.z,u0.w,u1.x,u1.y,u1.z,u1.w};
        float acc0=0.f, acc1=0.f, acc2=0.f, acc3=0.f;
        #pragma unroll
        for (int p = 0; p < 8; p++){
            float lo, hi;
            unpack2(uu[p], lo, hi);
            float4 wl = w3r[p*2], wh = w3r[p*2+1];
            acc0 += lo*wl.x + hi*wh.x;
            acc1 += lo*wl.y + hi*wh.y;
            acc2 += lo*wl.z + hi*wh.z;
            acc3 += lo*wl.w + hi*wh.w;
        }
        #pragma unroll
        for (int o = 32; o; o >>= 1){
            acc0 += __shfl_xor(acc0, o, 64); acc1 += __shfl_xor(acc1, o, 64);
            acc2 += __shfl_xor(acc2, o, 64); acc3 += __shfl_xor(acc3, o, 64);
        }
        if (lane == 0){
            *(float4*)(h3 + n*4) = make_float4(acc0, acc1, acc2, acc3);
            al3s[n] = acc0*s3F[0] + acc1*s3F[1] + acc2*s3F[2] + acc3*s3F[3];
            al3d[n] = acc0*s3F[16] + acc1*s3F[17] + acc2*s3F[18] + acc3*s3F[19];
        }
    }
    gbar(done2, 1);

    /* phase 2: aggregate, wave-per-node */
    float b30 = s3F[32], b31 = s3F[33], b32 = s3F[34], b33 = s3F[35];
    #pragma unroll 1
    for (int n = bid*4 + wave; n < N_NODES; n += NB*4){
        int beg = offs[n], end = offs[n+1];
        float ad = al3d[n];
        float m = -1e30f;
        for (int e = beg + lane; e < end; e += 64){
            float v = al3s[ssort[e]] + ad; v = v > 0.f ? v : NEG*v;
            m = fmaxf(m, v);
        }
        #pragma unroll
        for (int o = 32; o; o >>= 1) m = fmaxf(m, __shfl_xor(m, o, 64));
        float z = 0.f;
        for (int e = beg + lane; e < end; e += 64){
            float v = al3s[ssort[e]] + ad; v = v > 0.f ? v : NEG*v;
            z += __expf(v - m);
        }
        #pragma unroll
        for (int o = 32; o; o >>= 1) z += __shfl_xor(z, o, 64);
        float inv = 1.f / (z + 1e-16f);
        float a0=0.f, a1=0.f, a2=0.f, a3=0.f;
        for (int e = beg + lane; e < end; e += 64){
            int s = ssort[e];
            float v = al3s[s] + ad; v = v > 0.f ? v : NEG*v;
            float w = __expf(v - m) * inv;
            float4 hv = *(const float4*)(h3 + s*4);
            a0 += w*hv.x; a1 += w*hv.y; a2 += w*hv.z; a3 += w*hv.w;
        }
        #pragma unroll
        for (int o = 32; o; o >>= 1){
            a0 += __shfl_xor(a0, o, 64); a1 += __shfl_xor(a1, o, 64);
            a2 += __shfl_xor(a2, o, 64); a3 += __shfl_xor(a3, o, 64);
        }
        if (lane == 0){
            float r0 = fmaxf(a0 + b30, 0.f);
            float r1 = fmaxf(a1 + b31, 0.f);
            float r2 = fmaxf(a2 + b32, 0.f);
            float r3 = fmaxf(a3 + b33, 0.f);
            if (f32){
                float* o4 = (float*)out;
                o4[n*4+0]=r0; o4[n*4+1]=r1; o4[n*4+2]=r2; o4[n*4+3]=r3;
            } else {
                ushort_t* o2 = (ushort_t*)out;
                o2[n*4+0]=f2bf(r0); o2[n*4+1]=f2bf(r1); o2[n*4+2]=f2bf(r2); o2[n*4+3]=f2bf(r3);
            }
        }
    }
}

extern "C" void kernel_launch(void* const* d_in, const int* in_sizes, int n_in,
                              void* d_out, int out_size, void* d_ws, size_t ws_size,
                              hipStream_t stream){
    const void* x   = d_in[0];
    const void* ei  = d_in[1];
    const void* W1  = d_in[2];
    const void* W2  = d_in[6];
    const void* W3  = d_in[10];

    char* ws = (char*)d_ws;
    int* done      = (int*)(ws + O_DONE);
    int* done2     = (int*)(ws + O_DONE2);
    int* bsum      = (int*)(ws + O_BSUM);
    int* counts    = (int*)(ws + O_COUNTS);
    int* offs      = (int*)(ws + O_OFFS);
    int* cursors   = (int*)(ws + O_CURS);
    int* ssort     = (int*)(ws + O_SSORT);
    float* alS     = (float*)(ws + O_ALS);
    float* alD     = (float*)(ws + O_ALD);
    float* al3s    = (float*)(ws + O_AL3S);
    float* al3d    = (float*)(ws + O_AL3D);
    float* h3      = (float*)(ws + O_H3);
    float* wvecF   = (float*)(ws + O_WVEC);
    float* W3F     = (float*)(ws + O_W3F);
    float* s3F     = (float*)(ws + O_S3F);
    ushort_t* W2T  = (ushort_t*)(ws + O_W2T);
    ushort_t* bufA = (ushort_t*)(ws + O_BUFA);
    ushort_t* bufB = (ushort_t*)(ws + O_BUFB);

    FrontArgs fa;
    fa.vsrc[0]=d_in[3];  fa.vsrc[1]=d_in[4];  fa.vsrc[2]=d_in[5];
    fa.vsrc[3]=d_in[7];  fa.vsrc[4]=d_in[8];  fa.vsrc[5]=d_in[9];
    fa.w3src = W3;
    fa.s3src[0]=d_in[11]; fa.s3src[1]=d_in[12]; fa.s3src[2]=d_in[13];

    k_front<<<NB, 256, 0, stream>>>(x, ei, W1, W2, fa, wvecF, W3F, s3F, W2T,
                                    counts, offs, cursors, ssort, bsum, done,
                                    bufA, alS, alD);
    k_gat_agg<<<5000, 256, 0, stream>>>(bufA, alS, alD, offs, ssort, wvecF + 2*1024, bufB);
    k_gemm2<<<640, 256, 0, stream>>>(bufB, W2T, bufA, wvecF + 3*1024, wvecF + 4*1024, alS, alD);
    k_gat_agg<<<5000, 256, 0, stream>>>(bufA, alS, alD, offs, ssort, wvecF + 5*1024, bufB);
    k_tail<<<NB, 256, 0, stream>>>(bufB, W3F, s3F, offs, ssort, (const uint32*)W1,
                                   h3, al3s, al3d, done2, d_out);
}

// Round 7
// 358.265 us; speedup vs baseline: 1.8366x; 1.8366x over previous
//
#include <hip/hip_runtime.h>

typedef unsigned short ushort_t;
typedef unsigned int uint32;

#define N_NODES 10000
#define N_EDGES 160000
#define ET (N_NODES + N_EDGES)   /* 170000 edges incl self-loops */
#define HT 1024                  /* heads * hid */
#define HEADS 8
#define NEG 0.2f

/* ---- ws layout (bytes). counts doubles as scatter cursors; layer-3 arrays
   overlay alS2/alD2 (free after layer-2 agg). Total ~45.14 MB (<= proven 45.24). */
#define O_FLAG     0
#define O_COUNTS   256                      /* 40192; also cursors */
#define O_OFFS     (O_COUNTS + 40192)
#define O_SSORT    (O_OFFS + 40192)         /* 680192 */
#define O_ALS1     (O_SSORT + 680192)       /* 320000 */
#define O_ALD1     (O_ALS1 + 320000)
#define O_ALS2     (O_ALD1 + 320000)        /* 320000, zeroed, atomic dots */
#define O_ALD2     (O_ALS2 + 320000)
#define O_AL3S     O_ALS2                   /* overlay: layer-3 phase only */
#define O_AL3D     (O_ALS2 + 40192)
#define O_H3       (O_ALS2 + 80384)
#define O_WVEC     (O_ALD2 + 320000)        /* 6x1024 floats */
#define O_W3F      (O_WVEC + 24576)
#define O_S3F      (O_W3F + 16384)
#define O_W2T      (O_S3F + 768)            /* bf16 [1024,1024] transposed */
#define O_BUFA     (O_W2T + 2097152)        /* h1/h2: 10000 rows bf16 */
#define O_BUFB     (O_BUFA + 20480000)      /* agg out: 10000 rows (staging clamped) */

__device__ __forceinline__ float bf2f(ushort_t u){ return __uint_as_float(((uint32)u) << 16); }
__device__ __forceinline__ ushort_t f2bf(float f){
    uint32 x = __float_as_uint(f);
    return (ushort_t)((x + 0x7fffu + ((x >> 16) & 1u)) >> 16);
}
__device__ __forceinline__ void unpack2(uint32 u, float& lo, float& hi){
    lo = __uint_as_float(u << 16);
    hi = __uint_as_float(u & 0xffff0000u);
}

typedef __bf16 bf16x8 __attribute__((ext_vector_type(8)));
typedef float  f32x4  __attribute__((ext_vector_type(4)));

typedef const __attribute__((address_space(1))) uint32* gas1_u32;
typedef       __attribute__((address_space(3))) uint32* las3_u32;

__device__ __forceinline__ void gload_lds16(const void* g, void* l){
    __builtin_amdgcn_global_load_lds((gas1_u32)g, (las3_u32)l, 16, 0, 0);
}

/* dtype probes (R1/R2 analysis) — run ONCE in k_probe, consumed via flags. */
__device__ __forceinline__ int probe_f32(const uint32* __restrict__ w){
    int cnt = 0;
    for (int i = 0; i < 256; i++){
        uint32 e = (w[i] >> 7) & 0xffu;
        cnt += (e >= 64u && e <= 160u) ? 1 : 0;
    }
    return (cnt > 200) ? 0 : 1;
}
__global__ void k_probe(const int* __restrict__ ei, const uint32* __restrict__ w1raw,
                        int* __restrict__ flags){
    if (threadIdx.x == 0){
        int nz = 0;
        for (int i = 0; i < 128; i++) nz |= ei[2*i + 1];
        flags[0] = (nz == 0) ? 1 : 0;
    }
    if (threadIdx.x == 1) flags[1] = probe_f32(w1raw);
}

__device__ __forceinline__ float cvt1(const void* p, int i, int f32){
    return f32 ? ((const float*)p)[i] : bf2f(((const ushort_t*)p)[i]);
}

/* ---------------- k_setup: conversions + zeros + W2 transpose (1202 blocks) ---------------- */
struct CvtArgs {
    const void* vsrc[6];   /* as1,ad1,b1,as2,ad2,b2 */
    const void* w3src;
    const void* s3src[3];  /* as3,ad3,b3 */
};

__global__ __launch_bounds__(256) void k_setup(CvtArgs a, const void* __restrict__ W2,
                                               const int* __restrict__ flags,
                                               float* __restrict__ wvecF, float* __restrict__ W3F,
                                               float* __restrict__ s3F,
                                               int* __restrict__ counts,
                                               float* __restrict__ alS2, float* __restrict__ alD2,
                                               ushort_t* __restrict__ W2T){
    __shared__ ushort_t tile[32][33];
    int b = blockIdx.x, tid = threadIdx.x;
    int f32 = flags[1];
    if (b < 11){
        int g = b * 1024 + tid * 4;
        #pragma unroll
        for (int j = 0; j < 4; j++){
            int i = g + j;
            if (i < 6144) wvecF[i] = cvt1(a.vsrc[i >> 10], i & 1023, f32);
            else if (i < 10240) W3F[i - 6144] = cvt1(a.w3src, i - 6144, f32);
            else if (i < 10252){
                int off = i - 10240;
                s3F[(off >> 2) * 16 + (off & 3)] = cvt1(a.s3src[off >> 2], off & 3, f32);
            }
        }
    } else if (b < 21){
        int g = (b - 11) * 1024 + tid * 4;
        #pragma unroll
        for (int j = 0; j < 4; j++) if (g + j < N_NODES) counts[g + j] = 0;
    } else if (b < 178){
        int g = (b - 21) * 1024 + tid * 4;
        if (g < 80000){ *(float4*)(alS2 + g) = make_float4(0,0,0,0); }
        else if (g < 160000){ *(float4*)(alD2 + g - 80000) = make_float4(0,0,0,0); }
    } else {
        int t = b - 178;
        int bx = t & 31, by = t >> 5;
        int cx = tid & 31, ry = (tid >> 5) * 4;
        #pragma unroll
        for (int r = 0; r < 4; r++){
            size_t idx = (size_t)(by*32 + ry + r)*1024 + bx*32 + cx;
            tile[ry + r][cx] = f32 ? f2bf(((const float*)W2)[idx]) : ((const ushort_t*)W2)[idx];
        }
        __syncthreads();
        #pragma unroll
        for (int r = 0; r < 4; r++)
            W2T[(size_t)(bx*32 + ry + r)*1024 + by*32 + cx] = tile[cx][ry + r];
    }
}

/* ---------------- extract edges (+self-loops), fused histogram ---------------- */
__global__ __launch_bounds__(256) void k_extract_hist(const void* __restrict__ ei, const int* __restrict__ flags,
                                                      int* __restrict__ counts){
    int i = blockIdx.x * 256 + threadIdx.x;
    int is64 = flags[0];
    int d = -1;
    if (i < N_EDGES){
        d = is64 ? (int)((const long long*)ei)[N_EDGES + i] : ((const int*)ei)[N_EDGES + i];
    } else if (i < ET){
        d = i - N_EDGES;
    }
    if (d >= 0) atomicAdd(&counts[d], 1);
}

/* single-block exclusive scan; cursors written back into counts buffer */
__global__ __launch_bounds__(1024) void k_scan(int* __restrict__ counts, int* __restrict__ offs, int n){
    __shared__ int wsum[16];
    __shared__ int running_s;
    int tid = threadIdx.x;
    int lane = tid & 63, wid = tid >> 6;
    if (tid == 0) running_s = 0;
    __syncthreads();
    for (int base = 0; base < n; base += 1024){
        int i = base + tid;
        int v = (i < n) ? counts[i] : 0;
        int x = v;
        #pragma unroll
        for (int d = 1; d < 64; d <<= 1){
            int t = __shfl_up(x, d, 64);
            if (lane >= d) x += t;
        }
        if (lane == 63) wsum[wid] = x;
        __syncthreads();
        if (wid == 0 && lane < 16){
            int w = wsum[lane];
            #pragma unroll
            for (int d = 1; d < 16; d <<= 1){
                int t = __shfl_up(w, d, 64);
                if (lane >= d) w += t;
            }
            wsum[lane] = w;
        }
        __syncthreads();
        int wprefix = (wid == 0) ? 0 : wsum[wid - 1];
        int run = running_s;
        int excl = run + wprefix + (x - v);
        if (i < n){ offs[i] = excl; counts[i] = excl; }   /* counts becomes cursors */
        __syncthreads();
        if (tid == 0) running_s = run + wsum[15];
        __syncthreads();
    }
    if (tid == 0) offs[n] = running_s;
}

__global__ __launch_bounds__(256) void k_scatter(const void* __restrict__ ei, const int* __restrict__ flags,
                                                 int* __restrict__ cursors, int* __restrict__ ssort){
    int i = blockIdx.x * 256 + threadIdx.x;
    if (i >= ET) return;
    int is64 = flags[0];
    int s, d;
    if (i < N_EDGES){
        if (is64){
            s = (int)((const long long*)ei)[i];
            d = (int)((const long long*)ei)[N_EDGES + i];
        } else {
            s = ((const int*)ei)[i];
            d = ((const int*)ei)[N_EDGES + i];
        }
    } else { s = i - N_EDGES; d = s; }
    int pos = atomicAdd(&cursors[d], 1);
    ssort[pos] = s;
}

/* ---------------- layer-1 GEMM fused with attention dots (W1 in LDS) ---------------- */
__global__ __launch_bounds__(256) void k_gemm1f(const void* __restrict__ x, const void* __restrict__ W1,
                                                const int* __restrict__ flags,
                                                const float* __restrict__ wvecF,
                                                ushort_t* __restrict__ h1,
                                                float* __restrict__ alS, float* __restrict__ alD){
    __shared__ float w1s[14 * HT];
    int tid = threadIdx.x;
    int f32 = flags[1];
    if (f32){
        for (int i = tid * 4; i < 14 * HT; i += 1024)
            *(float4*)(w1s + i) = *(const float4*)((const float*)W1 + i);
    } else {
        for (int i = tid * 4; i < 14 * HT; i += 1024){
            uint2 u = *(const uint2*)((const ushort_t*)W1 + i);
            unpack2(u.x, w1s[i], w1s[i+1]);
            unpack2(u.y, w1s[i+2], w1s[i+3]);
        }
    }
    __syncthreads();
    int c0 = tid * 4;
    float4 sv = *(const float4*)(wvecF + c0);
    float4 dv = *(const float4*)(wvecF + 1024 + c0);
    int head = tid >> 5, l32 = tid & 31;
    #pragma unroll 1
    for (int n = blockIdx.x; n < N_NODES; n += 512){
        float a0=0.f, a1=0.f, a2=0.f, a3=0.f;
        #pragma unroll
        for (int k = 0; k < 14; k++){
            float xv = f32 ? ((const float*)x)[n*14 + k] : bf2f(((const ushort_t*)x)[n*14 + k]);
            float4 w = *(const float4*)(w1s + k*HT + c0);
            a0 += xv*w.x; a1 += xv*w.y; a2 += xv*w.z; a3 += xv*w.w;
        }
        uint2 o;
        o.x = (uint32)f2bf(a0) | ((uint32)f2bf(a1) << 16);
        o.y = (uint32)f2bf(a2) | ((uint32)f2bf(a3) << 16);
        *(uint2*)(h1 + (size_t)n*HT + c0) = o;
        float h0,h1v,h2,h3v;
        unpack2(o.x, h0, h1v); unpack2(o.y, h2, h3v);
        float s = h0*sv.x + h1v*sv.y + h2*sv.z + h3v*sv.w;
        float d = h0*dv.x + h1v*dv.y + h2*dv.z + h3v*dv.w;
        #pragma unroll
        for (int of = 16; of; of >>= 1){ s += __shfl_xor(s, of, 32); d += __shfl_xor(d, of, 32); }
        if (l32 == 0){ alS[n*HEADS + head] = s; alD[n*HEADS + head] = d; }
    }
}

/* ---------------- fused segment-softmax + aggregate + bias + relu (v3.2) ----------------
   Barrier-free: 2 nodes/block, 2 waves/node; lane owns 8 channels; x8-unrolled gather. */
__global__ __launch_bounds__(256) void k_gat_agg(const ushort_t* __restrict__ H, const float* __restrict__ alS,
                                                 const float* __restrict__ alD, const int* __restrict__ offs,
                                                 const int* __restrict__ srcs, const float* __restrict__ bias,
                                                 ushort_t* __restrict__ out){
    int tid = threadIdx.x;
    int wv = tid >> 6, lane = tid & 63;
    int n = blockIdx.x * 2 + (wv >> 1);
    int half = wv & 1;
    int beg = offs[n], end = offs[n+1];
    int head = half*4 + (lane >> 4);
    int slot = lane & 15;
    float ad = alD[n*HEADS + head];

    float m = -1e30f, z = 0.f;
    for (int c = beg; c < end; c += 64){
        int cn = min(64, end - c);
        int sreg = (lane < cn) ? srcs[c + lane] : 0;
        for (int p = slot; p < cn; p += 16){
            int s = __shfl(sreg, p, 64);
            float v = alS[s*HEADS + head] + ad;
            v = v > 0.f ? v : NEG*v;
            if (v > m){ z = z*__expf(m - v) + 1.f; m = v; }
            else z += __expf(v - m);
        }
    }
    #pragma unroll
    for (int o = 1; o < 16; o <<= 1){
        float m2 = __shfl_xor(m, o, 64);
        float z2 = __shfl_xor(z, o, 64);
        float nm = fmaxf(m, m2);
        z = z*__expf(m - nm) + z2*__expf(m2 - nm);
        m = nm;
    }
    float inv = 1.f / (z + 1e-16f);

    int ch0 = half*512 + lane*8;
    const ushort_t* Hc = H + ch0;
    float c0=0.f,c1=0.f,c2=0.f,c3=0.f,c4=0.f,c5=0.f,c6=0.f,c7=0.f;
    for (int c = beg; c < end; c += 64){
        int cn = min(64, end - c);
        int sreg = (lane < cn) ? srcs[c + lane] : 0;
        int j = 0;
        for (; j + 8 <= cn; j += 8){
            int s[8]; uint4 u[8]; float w[8];
            #pragma unroll
            for (int q = 0; q < 8; q++) s[q] = __shfl(sreg, j + q, 64);
            #pragma unroll
            for (int q = 0; q < 8; q++) u[q] = *(const uint4*)(Hc + (size_t)s[q]*HT);
            #pragma unroll
            for (int q = 0; q < 8; q++){
                float v = alS[s[q]*HEADS + head] + ad;
                v = v > 0.f ? v : NEG*v;
                w[q] = __expf(v - m) * inv;
            }
            #pragma unroll
            for (int q = 0; q < 8; q++){
                float f0,f1,f2,f3,f4,f5,f6,f7;
                unpack2(u[q].x,f0,f1); unpack2(u[q].y,f2,f3);
                unpack2(u[q].z,f4,f5); unpack2(u[q].w,f6,f7);
                c0+=w[q]*f0; c1+=w[q]*f1; c2+=w[q]*f2; c3+=w[q]*f3;
                c4+=w[q]*f4; c5+=w[q]*f5; c6+=w[q]*f6; c7+=w[q]*f7;
            }
        }
        for (; j < cn; j++){
            int s0 = __shfl(sreg, j, 64);
            uint4 u0 = *(const uint4*)(Hc + (size_t)s0*HT);
            float v0 = alS[s0*HEADS + head] + ad;
            v0 = v0 > 0.f ? v0 : NEG*v0;
            float w0 = __expf(v0 - m) * inv;
            float f0,f1,f2,f3,f4,f5,f6,f7;
            unpack2(u0.x,f0,f1); unpack2(u0.y,f2,f3); unpack2(u0.z,f4,f5); unpack2(u0.w,f6,f7);
            c0+=w0*f0; c1+=w0*f1; c2+=w0*f2; c3+=w0*f3;
            c4+=w0*f4; c5+=w0*f5; c6+=w0*f6; c7+=w0*f7;
        }
    }
    float4 b0 = *(const float4*)(bias + ch0);
    float4 b1 = *(const float4*)(bias + ch0 + 4);
    c0 = fmaxf(c0+b0.x, 0.f); c1 = fmaxf(c1+b0.y, 0.f);
    c2 = fmaxf(c2+b0.z, 0.f); c3 = fmaxf(c3+b0.w, 0.f);
    c4 = fmaxf(c4+b1.x, 0.f); c5 = fmaxf(c5+b1.y, 0.f);
    c6 = fmaxf(c6+b1.z, 0.f); c7 = fmaxf(c7+b1.w, 0.f);
    uint4 o;
    o.x = (uint32)f2bf(c0) | ((uint32)f2bf(c1) << 16);
    o.y = (uint32)f2bf(c2) | ((uint32)f2bf(c3) << 16);
    o.z = (uint32)f2bf(c4) | ((uint32)f2bf(c5) << 16);
    o.w = (uint32)f2bf(c6) | ((uint32)f2bf(c7) << 16);
    *(uint4*)(out + (size_t)n*HT + ch0) = o;
}

/* ---------------- layer-2 GEMM: bf16 MFMA, 128x64 tiles (1264 blocks) ----------------
   N split to 64 for 2x TLP (R4/R5 evidence: latency-bound at 632 blocks, not BW
   or conflicts). Plain LDS layout (fastest measured). Partial attention dots ->
   atomicAdd into zeroed alS2/alD2. A-staging row-clamped so bufB needs no pad rows. */
__global__ __launch_bounds__(256) void k_gemm2(const ushort_t* __restrict__ A, const ushort_t* __restrict__ BT,
                                               ushort_t* __restrict__ C,
                                               const float* __restrict__ aS, const float* __restrict__ aD,
                                               float* __restrict__ alS2, float* __restrict__ alD2){
    __shared__ ushort_t lA[128*32];   /* 8 KB */
    __shared__ ushort_t lB[64*32];    /* 4 KB */
    int bn = blockIdx.x, bm = blockIdx.y;   /* x fast: 16 bn-blocks share one A tile */
    int tid = threadIdx.x;
    int lane = tid & 63;
    int wave = tid >> 6;
    int wm = wave * 32;
    int lm = lane & 15, kg = lane >> 4;
    f32x4 acc[2][4];
    #pragma unroll
    for (int i = 0; i < 2; i++)
        #pragma unroll
        for (int j = 0; j < 4; j++) acc[i][j] = (f32x4)0.0f;

    int rowA0 = bm * 128, rowB0 = bn * 64;
    for (int k0 = 0; k0 < 1024; k0 += 32){
        #pragma unroll
        for (int it = 0; it < 2; ++it){
            int s = tid + it*256;
            int r = s >> 2, q = s & 3;
            int ra = rowA0 + r; if (ra > N_NODES-1) ra = N_NODES-1;
            gload_lds16(A + (size_t)ra*1024 + k0 + q*8, lA + s*8);
        }
        {
            int r = tid >> 2, q = tid & 3;
            gload_lds16(BT + (size_t)(rowB0 + r)*1024 + k0 + q*8, lB + tid*8);
        }
        __syncthreads();
        bf16x8 af[2], bfr[4];
        #pragma unroll
        for (int mt = 0; mt < 2; mt++) af[mt]  = *(const bf16x8*)(lA + (wm + mt*16 + lm)*32 + kg*8);
        #pragma unroll
        for (int nt = 0; nt < 4; nt++) bfr[nt] = *(const bf16x8*)(lB + (nt*16 + lm)*32 + kg*8);
        #pragma unroll
        for (int mt = 0; mt < 2; mt++)
            #pragma unroll
            for (int nt = 0; nt < 4; nt++)
                acc[mt][nt] = __builtin_amdgcn_mfma_f32_16x16x32_bf16(af[mt], bfr[nt], acc[mt][nt], 0, 0, 0);
        __syncthreads();
    }
    #pragma unroll
    for (int mt = 0; mt < 2; mt++){
        int row_base = bm*128 + wm + mt*16 + kg*4;
        #pragma unroll
        for (int nt = 0; nt < 4; nt++){
            int col = bn*64 + nt*16 + lm;
            #pragma unroll
            for (int r = 0; r < 4; r++){
                int row = row_base + r;
                if (row < N_NODES) C[(size_t)row*HT + col] = f2bf(acc[mt][nt][r]);
            }
        }
    }
    /* partial attention dots over this block's 64 cols (head = bn>>1) */
    int head = bn >> 1;
    float as_l[4], ad_l[4];
    #pragma unroll
    for (int nt = 0; nt < 4; nt++){
        as_l[nt] = aS[bn*64 + nt*16 + lm];
        ad_l[nt] = aD[bn*64 + nt*16 + lm];
    }
    #pragma unroll
    for (int mt = 0; mt < 2; mt++){
        #pragma unroll
        for (int r = 0; r < 4; r++){
            float ps = acc[mt][0][r]*as_l[0] + acc[mt][1][r]*as_l[1]
                     + acc[mt][2][r]*as_l[2] + acc[mt][3][r]*as_l[3];
            float pd = acc[mt][0][r]*ad_l[0] + acc[mt][1][r]*ad_l[1]
                     + acc[mt][2][r]*ad_l[2] + acc[mt][3][r]*ad_l[3];
            #pragma unroll
            for (int o = 1; o < 16; o <<= 1){ ps += __shfl_xor(ps, o, 64); pd += __shfl_xor(pd, o, 64); }
            if (lm == 0){
                int row = bm*128 + wm + mt*16 + kg*4 + r;
                if (row < N_NODES){
                    atomicAdd(&alS2[row*HEADS + head], ps);
                    atomicAdd(&alD2[row*HEADS + head], pd);
                }
            }
        }
    }
}

/* ---------------- layer-3 GEMM: wave-per-node, W3 in registers ---------------- */
__global__ __launch_bounds__(256) void k_gemm3(const ushort_t* __restrict__ A, const float* __restrict__ W3,
                                               const float* __restrict__ s3,
                                               float* __restrict__ h3, float* __restrict__ al3s, float* __restrict__ al3d){
    int tid = threadIdx.x;
    int lane = tid & 63, wave = tid >> 6;
    int n = blockIdx.x * 4 + wave;
    if (n >= N_NODES) return;
    float4 w3r[16];
    #pragma unroll
    for (int j = 0; j < 16; j++) w3r[j] = ((const float4*)W3)[lane*16 + j];
    const uint4* ap = (const uint4*)(A + (size_t)n*HT + lane*16);
    uint4 u0 = ap[0], u1 = ap[1];
    uint32 uu[8] = {u0.x,u0.y,u0.z,u0.w,u1.x,u1.y,u1.z,u1.w};
    float acc0=0.f, acc1=0.f, acc2=0.f, acc3=0.f;
    #pragma unroll
    for (int p = 0; p < 8; p++){
        float lo, hi;
        unpack2(uu[p], lo, hi);
        float4 wl = w3r[p*2], wh = w3r[p*2+1];
        acc0 += lo*wl.x + hi*wh.x;
        acc1 += lo*wl.y + hi*wh.y;
        acc2 += lo*wl.z + hi*wh.z;
        acc3 += lo*wl.w + hi*wh.w;
    }
    #pragma unroll
    for (int o = 32; o; o >>= 1){
        acc0 += __shfl_xor(acc0, o, 64); acc1 += __shfl_xor(acc1, o, 64);
        acc2 += __shfl_xor(acc2, o, 64); acc3 += __shfl_xor(acc3, o, 64);
    }
    if (lane == 0){
        *(float4*)(h3 + n*4) = make_float4(acc0, acc1, acc2, acc3);
        al3s[n] = acc0*s3[0] + acc1*s3[1] + acc2*s3[2] + acc3*s3[3];
        al3d[n] = acc0*s3[16] + acc1*s3[17] + acc2*s3[18] + acc3*s3[19];
    }
}

/* ---------------- layer-3 attention aggregate: wave-per-node ---------------- */
__global__ __launch_bounds__(256) void k_gat_agg3(const float* __restrict__ h3, const float* __restrict__ al3s,
                                                  const float* __restrict__ al3d, const int* __restrict__ offs,
                                                  const int* __restrict__ srcs, const float* __restrict__ b3,
                                                  const int* __restrict__ flags, void* __restrict__ out){
    int tid = threadIdx.x;
    int l = tid & 63, wave = tid >> 6;
    int n = blockIdx.x * 4 + wave;
    if (n >= N_NODES) return;
    int beg = offs[n], end = offs[n+1];
    float ad = al3d[n];
    float m = -1e30f;
    for (int e = beg + l; e < end; e += 64){
        float v = al3s[srcs[e]] + ad; v = v > 0.f ? v : NEG*v;
        m = fmaxf(m, v);
    }
    #pragma unroll
    for (int o = 32; o; o >>= 1) m = fmaxf(m, __shfl_xor(m, o, 64));
    float z = 0.f;
    for (int e = beg + l; e < end; e += 64){
        float v = al3s[srcs[e]] + ad; v = v > 0.f ? v : NEG*v;
        z += __expf(v - m);
    }
    #pragma unroll
    for (int o = 32; o; o >>= 1) z += __shfl_xor(z, o, 64);
    float inv = 1.f / (z + 1e-16f);
    float a0=0.f, a1=0.f, a2=0.f, a3=0.f;
    for (int e = beg + l; e < end; e += 64){
        int s = srcs[e];
        float v = al3s[s] + ad; v = v > 0.f ? v : NEG*v;
        float w = __expf(v - m) * inv;
        float4 hv = *(const float4*)(h3 + s*4);
        a0 += w*hv.x; a1 += w*hv.y; a2 += w*hv.z; a3 += w*hv.w;
    }
    #pragma unroll
    for (int o = 32; o; o >>= 1){
        a0 += __shfl_xor(a0, o, 64); a1 += __shfl_xor(a1, o, 64);
        a2 += __shfl_xor(a2, o, 64); a3 += __shfl_xor(a3, o, 64);
    }
    if (l == 0){
        float r0 = fmaxf(a0 + b3[0], 0.f);
        float r1 = fmaxf(a1 + b3[1], 0.f);
        float r2 = fmaxf(a2 + b3[2], 0.f);
        float r3 = fmaxf(a3 + b3[3], 0.f);
        if (flags[1]){
            float* o4 = (float*)out;
            o4[n*4+0]=r0; o4[n*4+1]=r1; o4[n*4+2]=r2; o4[n*4+3]=r3;
        } else {
            ushort_t* o2 = (ushort_t*)out;
            o2[n*4+0]=f2bf(r0); o2[n*4+1]=f2bf(r1); o2[n*4+2]=f2bf(r2); o2[n*4+3]=f2bf(r3);
        }
    }
}

extern "C" void kernel_launch(void* const* d_in, const int* in_sizes, int n_in,
                              void* d_out, int out_size, void* d_ws, size_t ws_size,
                              hipStream_t stream){
    const void* x   = d_in[0];
    const void* ei  = d_in[1];
    const void* W1  = d_in[2];
    const void* W2  = d_in[6];
    const void* W3  = d_in[10];

    char* ws = (char*)d_ws;
    int* flags     = (int*)(ws + O_FLAG);
    int* counts    = (int*)(ws + O_COUNTS);   /* also cursors */
    int* offs      = (int*)(ws + O_OFFS);
    int* ssort     = (int*)(ws + O_SSORT);
    float* alS1    = (float*)(ws + O_ALS1);
    float* alD1    = (float*)(ws + O_ALD1);
    float* alS2    = (float*)(ws + O_ALS2);
    float* alD2    = (float*)(ws + O_ALD2);
    float* al3s    = (float*)(ws + O_AL3S);
    float* al3d    = (float*)(ws + O_AL3D);
    float* h3      = (float*)(ws + O_H3);
    float* wvecF   = (float*)(ws + O_WVEC);
    float* W3F     = (float*)(ws + O_W3F);
    float* s3F     = (float*)(ws + O_S3F);
    ushort_t* W2T  = (ushort_t*)(ws + O_W2T);
    ushort_t* bufA = (ushort_t*)(ws + O_BUFA);
    ushort_t* bufB = (ushort_t*)(ws + O_BUFB);

    const int EB = (ET + 255) / 256;

    CvtArgs ca;
    ca.vsrc[0]=d_in[3];  ca.vsrc[1]=d_in[4];  ca.vsrc[2]=d_in[5];
    ca.vsrc[3]=d_in[7];  ca.vsrc[4]=d_in[8];  ca.vsrc[5]=d_in[9];
    ca.w3src = W3;
    ca.s3src[0]=d_in[11]; ca.s3src[1]=d_in[12]; ca.s3src[2]=d_in[13];

    k_probe<<<1, 64, 0, stream>>>((const int*)ei, (const uint32*)W1, flags);
    k_setup<<<1202, 256, 0, stream>>>(ca, W2, flags, wvecF, W3F, s3F, counts, alS2, alD2, W2T);
    k_extract_hist<<<EB, 256, 0, stream>>>(ei, flags, counts);
    k_scan<<<1, 1024, 0, stream>>>(counts, offs, N_NODES);
    k_scatter<<<EB, 256, 0, stream>>>(ei, flags, counts, ssort);

    /* layer 1 */
    k_gemm1f<<<512, 256, 0, stream>>>(x, W1, flags, wvecF, bufA, alS1, alD1);
    k_gat_agg<<<5000, 256, 0, stream>>>(bufA, alS1, alD1, offs, ssort, wvecF + 2*1024, bufB);

    /* layer 2 */
    k_gemm2<<<dim3(16, 79), 256, 0, stream>>>(bufB, W2T, bufA, wvecF + 3*1024, wvecF + 4*1024, alS2, alD2);
    k_gat_agg<<<5000, 256, 0, stream>>>(bufA, alS2, alD2, offs, ssort, wvecF + 5*1024, bufB);

    /* layer 3 */
    k_gemm3<<<2500, 256, 0, stream>>>(bufB, W3F, s3F, h3, al3s, al3d);
    k_gat_agg3<<<2500, 256, 0, stream>>>(h3, al3s, al3d, offs, ssort, s3F + 32, flags, d_out);
}

// Round 8
// 342.379 us; speedup vs baseline: 1.9218x; 1.0464x over previous
//
#include <hip/hip_runtime.h>

typedef unsigned short ushort_t;
typedef unsigned int uint32;

#define N_NODES 10000
#define N_EDGES 160000
#define ET (N_NODES + N_EDGES)   /* 170000 edges incl self-loops */
#define HT 1024                  /* heads * hid */
#define HEADS 8
#define NEG 0.2f

/* ---- ws layout (bytes). counts doubles as scatter cursors; layer-3 arrays
   overlay alS2/alD2 (free after layer-2 agg). */
#define O_FLAG     0
#define O_BND      64                       /* 32 uints: B1S[8] B1D[8] B2S[8] B2D[8] */
#define O_COUNTS   256                      /* 40192; also cursors */
#define O_OFFS     (O_COUNTS + 40192)
#define O_SSORT    (O_OFFS + 40192)         /* 680192 */
#define O_ALS1     (O_SSORT + 680192)       /* 320000 */
#define O_ALD1     (O_ALS1 + 320000)
#define O_ALS2     (O_ALD1 + 320000)        /* 320000, zeroed, atomic dots */
#define O_ALD2     (O_ALS2 + 320000)
#define O_AL3S     O_ALS2                   /* overlay: layer-3 phase only */
#define O_AL3D     (O_ALS2 + 40192)
#define O_H3       (O_ALS2 + 80384)
#define O_WVEC     (O_ALD2 + 320000)        /* 6x1024 floats */
#define O_W3F      (O_WVEC + 24576)
#define O_S3F      (O_W3F + 16384)
#define O_W2T      (O_S3F + 768)            /* bf16 [1024,1024] transposed */
#define O_BUFA     (O_W2T + 2097152)
#define O_BUFB     (O_BUFA + 20480000)

__device__ __forceinline__ float bf2f(ushort_t u){ return __uint_as_float(((uint32)u) << 16); }
__device__ __forceinline__ ushort_t f2bf(float f){
    uint32 x = __float_as_uint(f);
    return (ushort_t)((x + 0x7fffu + ((x >> 16) & 1u)) >> 16);
}
__device__ __forceinline__ void unpack2(uint32 u, float& lo, float& hi){
    lo = __uint_as_float(u << 16);
    hi = __uint_as_float(u & 0xffff0000u);
}

typedef __bf16 bf16x8 __attribute__((ext_vector_type(8)));
typedef float  f32x4  __attribute__((ext_vector_type(4)));

typedef const __attribute__((address_space(1))) uint32* gas1_u32;
typedef       __attribute__((address_space(3))) uint32* las3_u32;

__device__ __forceinline__ void gload_lds16(const void* g, void* l){
    __builtin_amdgcn_global_load_lds((gas1_u32)g, (las3_u32)l, 16, 0, 0);
}

/* dtype probes (R1/R2 analysis) — run ONCE in k_probe, consumed via flags. */
__device__ __forceinline__ int probe_f32(const uint32* __restrict__ w){
    int cnt = 0;
    for (int i = 0; i < 256; i++){
        uint32 e = (w[i] >> 7) & 0xffu;
        cnt += (e >= 64u && e <= 160u) ? 1 : 0;
    }
    return (cnt > 200) ? 0 : 1;
}
__global__ void k_probe(const int* __restrict__ ei, const uint32* __restrict__ w1raw,
                        int* __restrict__ flags){
    if (threadIdx.x == 0){
        int nz = 0;
        for (int i = 0; i < 128; i++) nz |= ei[2*i + 1];
        flags[0] = (nz == 0) ? 1 : 0;
    }
    if (threadIdx.x == 1) flags[1] = probe_f32(w1raw);
}

__device__ __forceinline__ float cvt1(const void* p, int i, int f32){
    return f32 ? ((const float*)p)[i] : bf2f(((const ushort_t*)p)[i]);
}

/* ---------------- k_setup: conversions + zeros + W2 transpose (1202 blocks) ---------------- */
struct CvtArgs {
    const void* vsrc[6];   /* as1,ad1,b1,as2,ad2,b2 */
    const void* w3src;
    const void* s3src[3];  /* as3,ad3,b3 */
};

__global__ __launch_bounds__(256) void k_setup(CvtArgs a, const void* __restrict__ W2,
                                               const int* __restrict__ flags,
                                               float* __restrict__ wvecF, float* __restrict__ W3F,
                                               float* __restrict__ s3F,
                                               int* __restrict__ counts,
                                               float* __restrict__ alS2, float* __restrict__ alD2,
                                               uint32* __restrict__ bnd,
                                               ushort_t* __restrict__ W2T){
    __shared__ ushort_t tile[32][33];
    int b = blockIdx.x, tid = threadIdx.x;
    int f32 = flags[1];
    if (b < 11){
        if (b == 0 && tid < 32) bnd[tid] = 0;   /* zero softmax-bound slots */
        int g = b * 1024 + tid * 4;
        #pragma unroll
        for (int j = 0; j < 4; j++){
            int i = g + j;
            if (i < 6144) wvecF[i] = cvt1(a.vsrc[i >> 10], i & 1023, f32);
            else if (i < 10240) W3F[i - 6144] = cvt1(a.w3src, i - 6144, f32);
            else if (i < 10252){
                int off = i - 10240;
                s3F[(off >> 2) * 16 + (off & 3)] = cvt1(a.s3src[off >> 2], off & 3, f32);
            }
        }
    } else if (b < 21){
        int g = (b - 11) * 1024 + tid * 4;
        #pragma unroll
        for (int j = 0; j < 4; j++) if (g + j < N_NODES) counts[g + j] = 0;
    } else if (b < 178){
        int g = (b - 21) * 1024 + tid * 4;
        if (g < 80000){ *(float4*)(alS2 + g) = make_float4(0,0,0,0); }
        else if (g < 160000){ *(float4*)(alD2 + g - 80000) = make_float4(0,0,0,0); }
    } else {
        int t = b - 178;
        int bx = t & 31, by = t >> 5;
        int cx = tid & 31, ry = (tid >> 5) * 4;
        #pragma unroll
        for (int r = 0; r < 4; r++){
            size_t idx = (size_t)(by*32 + ry + r)*1024 + bx*32 + cx;
            tile[ry + r][cx] = f32 ? f2bf(((const float*)W2)[idx]) : ((const ushort_t*)W2)[idx];
        }
        __syncthreads();
        #pragma unroll
        for (int r = 0; r < 4; r++)
            W2T[(size_t)(bx*32 + ry + r)*1024 + by*32 + cx] = tile[cx][ry + r];
    }
}

/* ---------------- extract edges (+self-loops), fused histogram ---------------- */
__global__ __launch_bounds__(256) void k_extract_hist(const void* __restrict__ ei, const int* __restrict__ flags,
                                                      int* __restrict__ counts){
    int i = blockIdx.x * 256 + threadIdx.x;
    int is64 = flags[0];
    int d = -1;
    if (i < N_EDGES){
        d = is64 ? (int)((const long long*)ei)[N_EDGES + i] : ((const int*)ei)[N_EDGES + i];
    } else if (i < ET){
        d = i - N_EDGES;
    }
    if (d >= 0) atomicAdd(&counts[d], 1);
}

/* single-block exclusive scan; cursors written back into counts buffer */
__global__ __launch_bounds__(1024) void k_scan(int* __restrict__ counts, int* __restrict__ offs, int n){
    __shared__ int wsum[16];
    __shared__ int running_s;
    int tid = threadIdx.x;
    int lane = tid & 63, wid = tid >> 6;
    if (tid == 0) running_s = 0;
    __syncthreads();
    for (int base = 0; base < n; base += 1024){
        int i = base + tid;
        int v = (i < n) ? counts[i] : 0;
        int x = v;
        #pragma unroll
        for (int d = 1; d < 64; d <<= 1){
            int t = __shfl_up(x, d, 64);
            if (lane >= d) x += t;
        }
        if (lane == 63) wsum[wid] = x;
        __syncthreads();
        if (wid == 0 && lane < 16){
            int w = wsum[lane];
            #pragma unroll
            for (int d = 1; d < 16; d <<= 1){
                int t = __shfl_up(w, d, 64);
                if (lane >= d) w += t;
            }
            wsum[lane] = w;
        }
        __syncthreads();
        int wprefix = (wid == 0) ? 0 : wsum[wid - 1];
        int run = running_s;
        int excl = run + wprefix + (x - v);
        if (i < n){ offs[i] = excl; counts[i] = excl; }
        __syncthreads();
        if (tid == 0) running_s = run + wsum[15];
        __syncthreads();
    }
    if (tid == 0) offs[n] = running_s;
}

__global__ __launch_bounds__(256) void k_scatter(const void* __restrict__ ei, const int* __restrict__ flags,
                                                 int* __restrict__ cursors, int* __restrict__ ssort){
    int i = blockIdx.x * 256 + threadIdx.x;
    if (i >= ET) return;
    int is64 = flags[0];
    int s, d;
    if (i < N_EDGES){
        if (is64){
            s = (int)((const long long*)ei)[i];
            d = (int)((const long long*)ei)[N_EDGES + i];
        } else {
            s = ((const int*)ei)[i];
            d = ((const int*)ei)[N_EDGES + i];
        }
    } else { s = i - N_EDGES; d = s; }
    int pos = atomicAdd(&cursors[d], 1);
    ssort[pos] = s;
}

/* ---------------- layer-1 GEMM + attention dots + fused per-head bound B1 ---------------- */
__global__ __launch_bounds__(256) void k_gemm1f(const void* __restrict__ x, const void* __restrict__ W1,
                                                const int* __restrict__ flags,
                                                const float* __restrict__ wvecF,
                                                ushort_t* __restrict__ h1,
                                                float* __restrict__ alS, float* __restrict__ alD,
                                                uint32* __restrict__ bnd){
    __shared__ float w1s[14 * HT];
    __shared__ uint32 smax[16];
    int tid = threadIdx.x;
    int f32 = flags[1];
    if (tid < 16) smax[tid] = 0;
    if (f32){
        for (int i = tid * 4; i < 14 * HT; i += 1024)
            *(float4*)(w1s + i) = *(const float4*)((const float*)W1 + i);
    } else {
        for (int i = tid * 4; i < 14 * HT; i += 1024){
            uint2 u = *(const uint2*)((const ushort_t*)W1 + i);
            unpack2(u.x, w1s[i], w1s[i+1]);
            unpack2(u.y, w1s[i+2], w1s[i+3]);
        }
    }
    __syncthreads();
    int c0 = tid * 4;
    float4 sv = *(const float4*)(wvecF + c0);
    float4 dv = *(const float4*)(wvecF + 1024 + c0);
    int head = tid >> 5, l32 = tid & 31;
    #pragma unroll 1
    for (int n = blockIdx.x; n < N_NODES; n += 512){
        float a0=0.f, a1=0.f, a2=0.f, a3=0.f;
        #pragma unroll
        for (int k = 0; k < 14; k++){
            float xv = f32 ? ((const float*)x)[n*14 + k] : bf2f(((const ushort_t*)x)[n*14 + k]);
            float4 w = *(const float4*)(w1s + k*HT + c0);
            a0 += xv*w.x; a1 += xv*w.y; a2 += xv*w.z; a3 += xv*w.w;
        }
        uint2 o;
        o.x = (uint32)f2bf(a0) | ((uint32)f2bf(a1) << 16);
        o.y = (uint32)f2bf(a2) | ((uint32)f2bf(a3) << 16);
        *(uint2*)(h1 + (size_t)n*HT + c0) = o;
        float h0,h1v,h2,h3v;
        unpack2(o.x, h0, h1v); unpack2(o.y, h2, h3v);
        float s = h0*sv.x + h1v*sv.y + h2*sv.z + h3v*sv.w;
        float d = h0*dv.x + h1v*dv.y + h2*dv.z + h3v*dv.w;
        #pragma unroll
        for (int of = 16; of; of >>= 1){ s += __shfl_xor(s, of, 32); d += __shfl_xor(d, of, 32); }
        if (l32 == 0){
            alS[n*HEADS + head] = s; alD[n*HEADS + head] = d;
            atomicMax(&smax[head],     __float_as_uint(fmaxf(s, 0.f)));
            atomicMax(&smax[8 + head], __float_as_uint(fmaxf(d, 0.f)));
        }
    }
    __syncthreads();
    if (tid < 16) atomicMax(&bnd[tid], smax[tid]);
}

/* ---------------- per-head bound for layer 2 (alS2/alD2 after atomic dots) ---------------- */
__global__ __launch_bounds__(256) void k_bound(const float* __restrict__ alS2, const float* __restrict__ alD2,
                                               uint32* __restrict__ bnd){
    int g = blockIdx.x * 256 + threadIdx.x;
    int lane = threadIdx.x & 63;
    float ms = 0.f, md = 0.f;
    for (int i = g; i < 80000; i += 10240){ ms = fmaxf(ms, alS2[i]); md = fmaxf(md, alD2[i]); }
    #pragma unroll
    for (int o = 8; o < 64; o <<= 1){
        ms = fmaxf(ms, __shfl_xor(ms, o, 64));
        md = fmaxf(md, __shfl_xor(md, o, 64));
    }
    if (lane < 8){
        atomicMax(&bnd[16 + lane], __float_as_uint(ms));
        atomicMax(&bnd[24 + lane], __float_as_uint(md));
    }
}

/* ---------------- fused segment-softmax + aggregate + bias + relu (v4) ----------------
   SINGLE PASS: per-head global upper bound B (maxS+maxD, clamped >=0) replaces the
   per-node max sweep — exp(v-B) in [~1e-35, 1], ratios exact in fp32. z and the
   weighted sum accumulate together; divide at the end. 2 nodes/block, 2 waves/node,
   lane owns 8 channels, x8-unrolled gathers. */
__global__ __launch_bounds__(256) void k_gat_agg(const ushort_t* __restrict__ H, const float* __restrict__ alS,
                                                 const float* __restrict__ alD, const uint32* __restrict__ bnd,
                                                 int bo, const int* __restrict__ offs,
                                                 const int* __restrict__ srcs, const float* __restrict__ bias,
                                                 ushort_t* __restrict__ out){
    int tid = threadIdx.x;
    int wv = tid >> 6, lane = tid & 63;
    int n = blockIdx.x * 2 + (wv >> 1);
    int half = wv & 1;
    int beg = offs[n], end = offs[n+1];
    int head = half*4 + (lane >> 4);
    float ad = alD[n*HEADS + head];
    float B = __uint_as_float(bnd[bo + head]) + __uint_as_float(bnd[bo + 8 + head]);

    int ch0 = half*512 + lane*8;
    const ushort_t* Hc = H + ch0;
    float z = 0.f;
    float c0=0.f,c1=0.f,c2=0.f,c3=0.f,c4=0.f,c5=0.f,c6=0.f,c7=0.f;
    for (int c = beg; c < end; c += 64){
        int cn = min(64, end - c);
        int sreg = (lane < cn) ? srcs[c + lane] : 0;
        int j = 0;
        for (; j + 8 <= cn; j += 8){
            int s[8]; uint4 u[8]; float e[8];
            #pragma unroll
            for (int q = 0; q < 8; q++) s[q] = __shfl(sreg, j + q, 64);
            #pragma unroll
            for (int q = 0; q < 8; q++) u[q] = *(const uint4*)(Hc + (size_t)s[q]*HT);
            #pragma unroll
            for (int q = 0; q < 8; q++) e[q] = alS[s[q]*HEADS + head];
            #pragma unroll
            for (int q = 0; q < 8; q++){
                float v = e[q] + ad;
                v = v > 0.f ? v : NEG*v;
                float w = __expf(v - B);
                z += w;
                float f0,f1,f2,f3,f4,f5,f6,f7;
                unpack2(u[q].x,f0,f1); unpack2(u[q].y,f2,f3);
                unpack2(u[q].z,f4,f5); unpack2(u[q].w,f6,f7);
                c0+=w*f0; c1+=w*f1; c2+=w*f2; c3+=w*f3;
                c4+=w*f4; c5+=w*f5; c6+=w*f6; c7+=w*f7;
            }
        }
        for (; j < cn; j++){
            int s0 = __shfl(sreg, j, 64);
            uint4 u0 = *(const uint4*)(Hc + (size_t)s0*HT);
            float v = alS[s0*HEADS + head] + ad;
            v = v > 0.f ? v : NEG*v;
            float w = __expf(v - B);
            z += w;
            float f0,f1,f2,f3,f4,f5,f6,f7;
            unpack2(u0.x,f0,f1); unpack2(u0.y,f2,f3); unpack2(u0.z,f4,f5); unpack2(u0.w,f6,f7);
            c0+=w*f0; c1+=w*f1; c2+=w*f2; c3+=w*f3;
            c4+=w*f4; c5+=w*f5; c6+=w*f6; c7+=w*f7;
        }
    }
    float inv = 1.f / z;
    float4 b0 = *(const float4*)(bias + ch0);
    float4 b1 = *(const float4*)(bias + ch0 + 4);
    c0 = fmaxf(c0*inv + b0.x, 0.f); c1 = fmaxf(c1*inv + b0.y, 0.f);
    c2 = fmaxf(c2*inv + b0.z, 0.f); c3 = fmaxf(c3*inv + b0.w, 0.f);
    c4 = fmaxf(c4*inv + b1.x, 0.f); c5 = fmaxf(c5*inv + b1.y, 0.f);
    c6 = fmaxf(c6*inv + b1.z, 0.f); c7 = fmaxf(c7*inv + b1.w, 0.f);
    uint4 o;
    o.x = (uint32)f2bf(c0) | ((uint32)f2bf(c1) << 16);
    o.y = (uint32)f2bf(c2) | ((uint32)f2bf(c3) << 16);
    o.z = (uint32)f2bf(c4) | ((uint32)f2bf(c5) << 16);
    o.w = (uint32)f2bf(c6) | ((uint32)f2bf(c7) << 16);
    *(uint4*)(out + (size_t)n*HT + ch0) = o;
}

/* ---------------- layer-2 GEMM: bf16 MFMA, 128x64 tiles, BK=64, XOR-swizzled LDS ----------------
   BK=64 halves the barrier count per K (the structural stall — R4/R5/R7 evidence:
   conflicts, FETCH, occupancy all ruled out). LDS 24KB -> ~6 blocks/CU. XOR swizzle
   (phys quarter = q ^ (row&7)) makes fragment ds_read_b128 2-way (free). */
__global__ __launch_bounds__(256) void k_gemm2(const ushort_t* __restrict__ A, const ushort_t* __restrict__ BT,
                                               ushort_t* __restrict__ C,
                                               const float* __restrict__ aS, const float* __restrict__ aD,
                                               float* __restrict__ alS2, float* __restrict__ alD2){
    __shared__ ushort_t lA[128*64];   /* 16 KB */
    __shared__ ushort_t lB[64*64];    /* 8 KB */
    int bn = blockIdx.x, bm = blockIdx.y;
    int tid = threadIdx.x;
    int lane = tid & 63;
    int wave = tid >> 6;
    int wm = wave * 32;
    int lm = lane & 15, kg = lane >> 4;
    int swz = lm & 7;
    f32x4 acc[2][4];
    #pragma unroll
    for (int i = 0; i < 2; i++)
        #pragma unroll
        for (int j = 0; j < 4; j++) acc[i][j] = (f32x4)0.0f;

    int rowA0 = bm * 128, rowB0 = bn * 64;
    for (int k0 = 0; k0 < 1024; k0 += 64){
        #pragma unroll
        for (int it = 0; it < 4; ++it){
            int s = tid + it*256;
            int r = s >> 3, q = s & 7;
            int ra = rowA0 + r; if (ra > N_NODES-1) ra = N_NODES-1;
            gload_lds16(A + (size_t)ra*1024 + k0 + (q ^ (r & 7))*8, lA + s*8);
        }
        #pragma unroll
        for (int it = 0; it < 2; ++it){
            int s = tid + it*256;
            int r = s >> 3, q = s & 7;
            gload_lds16(BT + (size_t)(rowB0 + r)*1024 + k0 + (q ^ (r & 7))*8, lB + s*8);
        }
        __syncthreads();
        #pragma unroll
        for (int kh = 0; kh < 2; kh++){
            bf16x8 af[2], bfr[4];
            int qb = kh*4 + kg;
            int qp = (qb ^ swz) * 8;
            #pragma unroll
            for (int mt = 0; mt < 2; mt++) af[mt]  = *(const bf16x8*)(lA + (wm + mt*16 + lm)*64 + qp);
            #pragma unroll
            for (int nt = 0; nt < 4; nt++) bfr[nt] = *(const bf16x8*)(lB + (nt*16 + lm)*64 + qp);
            #pragma unroll
            for (int mt = 0; mt < 2; mt++)
                #pragma unroll
                for (int nt = 0; nt < 4; nt++)
                    acc[mt][nt] = __builtin_amdgcn_mfma_f32_16x16x32_bf16(af[mt], bfr[nt], acc[mt][nt], 0, 0, 0);
        }
        __syncthreads();
    }
    #pragma unroll
    for (int mt = 0; mt < 2; mt++){
        int row_base = bm*128 + wm + mt*16 + kg*4;
        #pragma unroll
        for (int nt = 0; nt < 4; nt++){
            int col = bn*64 + nt*16 + lm;
            #pragma unroll
            for (int r = 0; r < 4; r++){
                int row = row_base + r;
                if (row < N_NODES) C[(size_t)row*HT + col] = f2bf(acc[mt][nt][r]);
            }
        }
    }
    /* partial attention dots over this block's 64 cols (head = bn>>1) */
    int head = bn >> 1;
    float as_l[4], ad_l[4];
    #pragma unroll
    for (int nt = 0; nt < 4; nt++){
        as_l[nt] = aS[bn*64 + nt*16 + lm];
        ad_l[nt] = aD[bn*64 + nt*16 + lm];
    }
    #pragma unroll
    for (int mt = 0; mt < 2; mt++){
        #pragma unroll
        for (int r = 0; r < 4; r++){
            float ps = acc[mt][0][r]*as_l[0] + acc[mt][1][r]*as_l[1]
                     + acc[mt][2][r]*as_l[2] + acc[mt][3][r]*as_l[3];
            float pd = acc[mt][0][r]*ad_l[0] + acc[mt][1][r]*ad_l[1]
                     + acc[mt][2][r]*ad_l[2] + acc[mt][3][r]*ad_l[3];
            #pragma unroll
            for (int o = 1; o < 16; o <<= 1){ ps += __shfl_xor(ps, o, 64); pd += __shfl_xor(pd, o, 64); }
            if (lm == 0){
                int row = bm*128 + wm + mt*16 + kg*4 + r;
                if (row < N_NODES){
                    atomicAdd(&alS2[row*HEADS + head], ps);
                    atomicAdd(&alD2[row*HEADS + head], pd);
                }
            }
        }
    }
}

/* ---------------- layer-3 GEMM: wave-per-node, W3 in registers ---------------- */
__global__ __launch_bounds__(256) void k_gemm3(const ushort_t* __restrict__ A, const float* __restrict__ W3,
                                               const float* __restrict__ s3,
                                               float* __restrict__ h3, float* __restrict__ al3s, float* __restrict__ al3d){
    int tid = threadIdx.x;
    int lane = tid & 63, wave = tid >> 6;
    int n = blockIdx.x * 4 + wave;
    if (n >= N_NODES) return;
    float4 w3r[16];
    #pragma unroll
    for (int j = 0; j < 16; j++) w3r[j] = ((const float4*)W3)[lane*16 + j];
    const uint4* ap = (const uint4*)(A + (size_t)n*HT + lane*16);
    uint4 u0 = ap[0], u1 = ap[1];
    uint32 uu[8] = {u0.x,u0.y,u0.z,u0.w,u1.x,u1.y,u1.z,u1.w};
    float acc0=0.f, acc1=0.f, acc2=0.f, acc3=0.f;
    #pragma unroll
    for (int p = 0; p < 8; p++){
        float lo, hi;
        unpack2(uu[p], lo, hi);
        float4 wl = w3r[p*2], wh = w3r[p*2+1];
        acc0 += lo*wl.x + hi*wh.x;
        acc1 += lo*wl.y + hi*wh.y;
        acc2 += lo*wl.z + hi*wh.z;
        acc3 += lo*wl.w + hi*wh.w;
    }
    #pragma unroll
    for (int o = 32; o; o >>= 1){
        acc0 += __shfl_xor(acc0, o, 64); acc1 += __shfl_xor(acc1, o, 64);
        acc2 += __shfl_xor(acc2, o, 64); acc3 += __shfl_xor(acc3, o, 64);
    }
    if (lane == 0){
        *(float4*)(h3 + n*4) = make_float4(acc0, acc1, acc2, acc3);
        al3s[n] = acc0*s3[0] + acc1*s3[1] + acc2*s3[2] + acc3*s3[3];
        al3d[n] = acc0*s3[16] + acc1*s3[17] + acc2*s3[18] + acc3*s3[19];
    }
}

/* ---------------- layer-3 attention aggregate: wave-per-node ---------------- */
__global__ __launch_bounds__(256) void k_gat_agg3(const float* __restrict__ h3, const float* __restrict__ al3s,
                                                  const float* __restrict__ al3d, const int* __restrict__ offs,
                                                  const int* __restrict__ srcs, const float* __restrict__ b3,
                                                  const int* __restrict__ flags, void* __restrict__ out){
    int tid = threadIdx.x;
    int l = tid & 63, wave = tid >> 6;
    int n = blockIdx.x * 4 + wave;
    if (n >= N_NODES) return;
    int beg = offs[n], end = offs[n+1];
    float ad = al3d[n];
    float m = -1e30f;
    for (int e = beg + l; e < end; e += 64){
        float v = al3s[srcs[e]] + ad; v = v > 0.f ? v : NEG*v;
        m = fmaxf(m, v);
    }
    #pragma unroll
    for (int o = 32; o; o >>= 1) m = fmaxf(m, __shfl_xor(m, o, 64));
    float z = 0.f;
    for (int e = beg + l; e < end; e += 64){
        float v = al3s[srcs[e]] + ad; v = v > 0.f ? v : NEG*v;
        z += __expf(v - m);
    }
    #pragma unroll
    for (int o = 32; o; o >>= 1) z += __shfl_xor(z, o, 64);
    float inv = 1.f / (z + 1e-16f);
    float a0=0.f, a1=0.f, a2=0.f, a3=0.f;
    for (int e = beg + l; e < end; e += 64){
        int s = srcs[e];
        float v = al3s[s] + ad; v = v > 0.f ? v : NEG*v;
        float w = __expf(v - m) * inv;
        float4 hv = *(const float4*)(h3 + s*4);
        a0 += w*hv.x; a1 += w*hv.y; a2 += w*hv.z; a3 += w*hv.w;
    }
    #pragma unroll
    for (int o = 32; o; o >>= 1){
        a0 += __shfl_xor(a0, o, 64); a1 += __shfl_xor(a1, o, 64);
        a2 += __shfl_xor(a2, o, 64); a3 += __shfl_xor(a3, o, 64);
    }
    if (l == 0){
        float r0 = fmaxf(a0 + b3[0], 0.f);
        float r1 = fmaxf(a1 + b3[1], 0.f);
        float r2 = fmaxf(a2 + b3[2], 0.f);
        float r3 = fmaxf(a3 + b3[3], 0.f);
        if (flags[1]){
            float* o4 = (float*)out;
            o4[n*4+0]=r0; o4[n*4+1]=r1; o4[n*4+2]=r2; o4[n*4+3]=r3;
        } else {
            ushort_t* o2 = (ushort_t*)out;
            o2[n*4+0]=f2bf(r0); o2[n*4+1]=f2bf(r1); o2[n*4+2]=f2bf(r2); o2[n*4+3]=f2bf(r3);
        }
    }
}

extern "C" void kernel_launch(void* const* d_in, const int* in_sizes, int n_in,
                              void* d_out, int out_size, void* d_ws, size_t ws_size,
                              hipStream_t stream){
    const void* x   = d_in[0];
    const void* ei  = d_in[1];
    const void* W1  = d_in[2];
    const void* W2  = d_in[6];
    const void* W3  = d_in[10];

    char* ws = (char*)d_ws;
    int* flags     = (int*)(ws + O_FLAG);
    uint32* bnd    = (uint32*)(ws + O_BND);
    int* counts    = (int*)(ws + O_COUNTS);   /* also cursors */
    int* offs      = (int*)(ws + O_OFFS);
    int* ssort     = (int*)(ws + O_SSORT);
    float* alS1    = (float*)(ws + O_ALS1);
    float* alD1    = (float*)(ws + O_ALD1);
    float* alS2    = (float*)(ws + O_ALS2);
    float* alD2    = (float*)(ws + O_ALD2);
    float* al3s    = (float*)(ws + O_AL3S);
    float* al3d    = (float*)(ws + O_AL3D);
    float* h3      = (float*)(ws + O_H3);
    float* wvecF   = (float*)(ws + O_WVEC);
    float* W3F     = (float*)(ws + O_W3F);
    float* s3F     = (float*)(ws + O_S3F);
    ushort_t* W2T  = (ushort_t*)(ws + O_W2T);
    ushort_t* bufA = (ushort_t*)(ws + O_BUFA);
    ushort_t* bufB = (ushort_t*)(ws + O_BUFB);

    const int EB = (ET + 255) / 256;

    CvtArgs ca;
    ca.vsrc[0]=d_in[3];  ca.vsrc[1]=d_in[4];  ca.vsrc[2]=d_in[5];
    ca.vsrc[3]=d_in[7];  ca.vsrc[4]=d_in[8];  ca.vsrc[5]=d_in[9];
    ca.w3src = W3;
    ca.s3src[0]=d_in[11]; ca.s3src[1]=d_in[12]; ca.s3src[2]=d_in[13];

    k_probe<<<1, 64, 0, stream>>>((const int*)ei, (const uint32*)W1, flags);
    k_setup<<<1202, 256, 0, stream>>>(ca, W2, flags, wvecF, W3F, s3F, counts, alS2, alD2, bnd, W2T);
    k_extract_hist<<<EB, 256, 0, stream>>>(ei, flags, counts);
    k_scan<<<1, 1024, 0, stream>>>(counts, offs, N_NODES);
    k_scatter<<<EB, 256, 0, stream>>>(ei, flags, counts, ssort);

    /* layer 1 */
    k_gemm1f<<<512, 256, 0, stream>>>(x, W1, flags, wvecF, bufA, alS1, alD1, bnd);
    k_gat_agg<<<5000, 256, 0, stream>>>(bufA, alS1, alD1, bnd, 0, offs, ssort, wvecF + 2*1024, bufB);

    /* layer 2 */
    k_gemm2<<<dim3(16, 79), 256, 0, stream>>>(bufB, W2T, bufA, wvecF + 3*1024, wvecF + 4*1024, alS2, alD2);
    k_bound<<<40, 256, 0, stream>>>(alS2, alD2, bnd);
    k_gat_agg<<<5000, 256, 0, stream>>>(bufA, alS2, alD2, bnd, 16, offs, ssort, wvecF + 5*1024, bufB);

    /* layer 3 */
    k_gemm3<<<2500, 256, 0, stream>>>(bufB, W3F, s3F, h3, al3s, al3d);
    k_gat_agg3<<<2500, 256, 0, stream>>>(h3, al3s, al3d, offs, ssort, s3F + 32, flags, d_out);
}

// Round 9
// 335.026 us; speedup vs baseline: 1.9640x; 1.0219x over previous
//
#include <hip/hip_runtime.h>

typedef unsigned short ushort_t;
typedef unsigned int uint32;

#define N_NODES 10000
#define N_EDGES 160000
#define ET (N_NODES + N_EDGES)   /* 170000 edges incl self-loops */
#define HT 1024                  /* heads * hid */
#define HEADS 8
#define NEG 0.2f

/* ---- ws layout (bytes). counts doubles as scatter cursors; layer-3 arrays
   overlay alS2/alD2 (free after layer-2 agg). */
#define O_FLAG     0
#define O_BND      64                       /* 32 uints: B1S[8] B1D[8] B2S[8] B2D[8] */
#define O_BSUM     192                      /* 40 ints scan partials */
#define O_COUNTS   512                      /* 40192; also cursors */
#define O_OFFS     (O_COUNTS + 40192)
#define O_SSORT    (O_OFFS + 40192)         /* 680192 */
#define O_ALS1     (O_SSORT + 680192)       /* 320000 */
#define O_ALD1     (O_ALS1 + 320000)
#define O_ALS2     (O_ALD1 + 320000)        /* 320000, zeroed, atomic dots */
#define O_ALD2     (O_ALS2 + 320000)
#define O_AL3S     O_ALS2                   /* overlay: layer-3 phase only */
#define O_AL3D     (O_ALS2 + 40192)
#define O_H3       (O_ALS2 + 80384)
#define O_WVEC     (O_ALD2 + 320000)        /* 6x1024 floats */
#define O_W3F      (O_WVEC + 24576)
#define O_S3F      (O_W3F + 16384)
#define O_W2T      (O_S3F + 768)            /* bf16 [1024,1024] transposed */
#define O_BUFA     (O_W2T + 2097152)
#define O_BUFB     (O_BUFA + 20480000)

__device__ __forceinline__ float bf2f(ushort_t u){ return __uint_as_float(((uint32)u) << 16); }
__device__ __forceinline__ ushort_t f2bf(float f){
    uint32 x = __float_as_uint(f);
    return (ushort_t)((x + 0x7fffu + ((x >> 16) & 1u)) >> 16);
}
__device__ __forceinline__ void unpack2(uint32 u, float& lo, float& hi){
    lo = __uint_as_float(u << 16);
    hi = __uint_as_float(u & 0xffff0000u);
}

typedef __bf16 bf16x8 __attribute__((ext_vector_type(8)));
typedef float  f32x4  __attribute__((ext_vector_type(4)));

typedef const __attribute__((address_space(1))) uint32* gas1_u32;
typedef       __attribute__((address_space(3))) uint32* las3_u32;

__device__ __forceinline__ void gload_lds16(const void* g, void* l){
    __builtin_amdgcn_global_load_lds((gas1_u32)g, (las3_u32)l, 16, 0, 0);
}

/* dtype probes (R1/R2 analysis): bf16 low-element exponent concentrates near
   127; fp32 low 16 bits are uniform mantissa bits. Cheap (1KB L2-hot read) —
   recomputed per block where needed; flags published for later dispatches. */
__device__ __forceinline__ int probe_f32(const uint32* __restrict__ w){
    int cnt = 0;
    for (int i = 0; i < 256; i++){
        uint32 e = (w[i] >> 7) & 0xffu;
        cnt += (e >= 64u && e <= 160u) ? 1 : 0;
    }
    return (cnt > 200) ? 0 : 1;
}
__device__ __forceinline__ int probe_edge64(const int* __restrict__ ei){
    int nz = 0;
    for (int i = 0; i < 128; i++) nz |= ei[2*i + 1];
    return (nz == 0) ? 1 : 0;
}

__device__ __forceinline__ float cvt1(const void* p, int i, int f32){
    return f32 ? ((const float*)p)[i] : bf2f(((const ushort_t*)p)[i]);
}

/* ---------------- k_setup: flags + conversions + zeros + W2 transpose ---------------- */
struct CvtArgs {
    const void* vsrc[6];   /* as1,ad1,b1,as2,ad2,b2 */
    const void* w3src;
    const void* s3src[3];  /* as3,ad3,b3 */
};

__global__ __launch_bounds__(256) void k_setup(CvtArgs a, const void* __restrict__ W2,
                                               const uint32* __restrict__ w1raw,
                                               const int* __restrict__ eiraw,
                                               int* __restrict__ flags,
                                               float* __restrict__ wvecF, float* __restrict__ W3F,
                                               float* __restrict__ s3F,
                                               int* __restrict__ counts,
                                               float* __restrict__ alS2, float* __restrict__ alD2,
                                               uint32* __restrict__ bnd,
                                               ushort_t* __restrict__ W2T){
    __shared__ ushort_t tile[32][33];
    int b = blockIdx.x, tid = threadIdx.x;
    int f32 = probe_f32(w1raw);
    if (b < 11){
        if (b == 0){
            if (tid < 32) bnd[tid] = 0;
            if (tid == 32) flags[0] = probe_edge64(eiraw);
            if (tid == 33) flags[1] = f32;
        }
        int g = b * 1024 + tid * 4;
        #pragma unroll
        for (int j = 0; j < 4; j++){
            int i = g + j;
            if (i < 6144) wvecF[i] = cvt1(a.vsrc[i >> 10], i & 1023, f32);
            else if (i < 10240) W3F[i - 6144] = cvt1(a.w3src, i - 6144, f32);
            else if (i < 10252){
                int off = i - 10240;
                s3F[(off >> 2) * 16 + (off & 3)] = cvt1(a.s3src[off >> 2], off & 3, f32);
            }
        }
    } else if (b < 21){
        int g = (b - 11) * 1024 + tid * 4;
        #pragma unroll
        for (int j = 0; j < 4; j++) if (g + j < N_NODES) counts[g + j] = 0;
    } else if (b < 178){
        int g = (b - 21) * 1024 + tid * 4;
        if (g < 80000){ *(float4*)(alS2 + g) = make_float4(0,0,0,0); }
        else if (g < 160000){ *(float4*)(alD2 + g - 80000) = make_float4(0,0,0,0); }
    } else {
        int t = b - 178;
        int bx = t & 31, by = t >> 5;
        int cx = tid & 31, ry = (tid >> 5) * 4;
        #pragma unroll
        for (int r = 0; r < 4; r++){
            size_t idx = (size_t)(by*32 + ry + r)*1024 + bx*32 + cx;
            tile[ry + r][cx] = f32 ? f2bf(((const float*)W2)[idx]) : ((const ushort_t*)W2)[idx];
        }
        __syncthreads();
        #pragma unroll
        for (int r = 0; r < 4; r++)
            W2T[(size_t)(bx*32 + ry + r)*1024 + by*32 + cx] = tile[cx][ry + r];
    }
}

/* ---------------- k_exgemm1: extract/hist (blocks 0..664) ∥ layer-1 GEMM+dots
   (blocks 665..1176). Both depend only on k_setup; co-scheduled in one dispatch. */
__global__ __launch_bounds__(256) void k_exgemm1(const void* __restrict__ ei, const void* __restrict__ x,
                                                 const void* __restrict__ W1, const int* __restrict__ flags,
                                                 const float* __restrict__ wvecF,
                                                 int* __restrict__ counts,
                                                 ushort_t* __restrict__ h1,
                                                 float* __restrict__ alS, float* __restrict__ alD,
                                                 uint32* __restrict__ bnd){
    __shared__ float w1s[14 * HT];
    __shared__ uint32 smax[16];
    int bid = blockIdx.x, tid = threadIdx.x;
    if (bid < 665){
        /* extract + histogram */
        int i = bid * 256 + tid;
        int is64 = flags[0];
        int d = -1;
        if (i < N_EDGES){
            d = is64 ? (int)((const long long*)ei)[N_EDGES + i] : ((const int*)ei)[N_EDGES + i];
        } else if (i < ET){
            d = i - N_EDGES;
        }
        if (d >= 0) atomicAdd(&counts[d], 1);
        return;
    }
    /* layer-1 GEMM + attention dots + per-head bound B1 */
    int gb = bid - 665;             /* 0..511 */
    int f32 = flags[1];
    if (tid < 16) smax[tid] = 0;
    if (f32){
        for (int i = tid * 4; i < 14 * HT; i += 1024)
            *(float4*)(w1s + i) = *(const float4*)((const float*)W1 + i);
    } else {
        for (int i = tid * 4; i < 14 * HT; i += 1024){
            uint2 u = *(const uint2*)((const ushort_t*)W1 + i);
            unpack2(u.x, w1s[i], w1s[i+1]);
            unpack2(u.y, w1s[i+2], w1s[i+3]);
        }
    }
    __syncthreads();
    int c0 = tid * 4;
    float4 sv = *(const float4*)(wvecF + c0);
    float4 dv = *(const float4*)(wvecF + 1024 + c0);
    int head = tid >> 5, l32 = tid & 31;
    #pragma unroll 1
    for (int n = gb; n < N_NODES; n += 512){
        float a0=0.f, a1=0.f, a2=0.f, a3=0.f;
        #pragma unroll
        for (int k = 0; k < 14; k++){
            float xv = f32 ? ((const float*)x)[n*14 + k] : bf2f(((const ushort_t*)x)[n*14 + k]);
            float4 w = *(const float4*)(w1s + k*HT + c0);
            a0 += xv*w.x; a1 += xv*w.y; a2 += xv*w.z; a3 += xv*w.w;
        }
        uint2 o;
        o.x = (uint32)f2bf(a0) | ((uint32)f2bf(a1) << 16);
        o.y = (uint32)f2bf(a2) | ((uint32)f2bf(a3) << 16);
        *(uint2*)(h1 + (size_t)n*HT + c0) = o;
        float h0,h1v,h2,h3v;
        unpack2(o.x, h0, h1v); unpack2(o.y, h2, h3v);
        float s = h0*sv.x + h1v*sv.y + h2*sv.z + h3v*sv.w;
        float d = h0*dv.x + h1v*dv.y + h2*dv.z + h3v*dv.w;
        #pragma unroll
        for (int of = 16; of; of >>= 1){ s += __shfl_xor(s, of, 32); d += __shfl_xor(d, of, 32); }
        if (l32 == 0){
            alS[n*HEADS + head] = s; alD[n*HEADS + head] = d;
            atomicMax(&smax[head],     __float_as_uint(fmaxf(s, 0.f)));
            atomicMax(&smax[8 + head], __float_as_uint(fmaxf(d, 0.f)));
        }
    }
    __syncthreads();
    if (tid < 16) atomicMax(&bnd[tid], smax[tid]);
}

/* ---------------- parallel scan: 40-block sums, then 40-block scan ---------------- */
__global__ __launch_bounds__(256) void k_scan_a(const int* __restrict__ counts, int* __restrict__ bsum){
    __shared__ int ws[4];
    int b = blockIdx.x, tid = threadIdx.x;
    int i = b * 256 + tid;
    int v = (i < N_NODES) ? counts[i] : 0;
    int lane = tid & 63, wid = tid >> 6;
    #pragma unroll
    for (int o = 32; o; o >>= 1) v += __shfl_xor(v, o, 64);
    if (lane == 0) ws[wid] = v;
    __syncthreads();
    if (tid == 0) bsum[b] = ws[0] + ws[1] + ws[2] + ws[3];
}

__global__ __launch_bounds__(256) void k_scan_b(int* __restrict__ counts, const int* __restrict__ bsum,
                                                int* __restrict__ offs){
    __shared__ int ws[4];
    int b = blockIdx.x, tid = threadIdx.x;
    int i = b * 256 + tid;
    int v = (i < N_NODES) ? counts[i] : 0;
    int base = 0;
    #pragma unroll 1
    for (int j = 0; j < b; j++) base += bsum[j];
    int lane = tid & 63, wid = tid >> 6;
    int inc = v;
    #pragma unroll
    for (int d = 1; d < 64; d <<= 1){
        int t = __shfl_up(inc, d, 64);
        if (lane >= d) inc += t;
    }
    if (lane == 63) ws[wid] = inc;
    __syncthreads();
    int wpre = 0;
    #pragma unroll
    for (int j = 0; j < 4; j++) if (j < wid) wpre += ws[j];
    int excl = base + wpre + inc - v;
    if (i < N_NODES){ offs[i] = excl; counts[i] = excl; }  /* counts becomes cursors */
    if (i == N_NODES) offs[i] = excl;                      /* == ET */
}

__global__ __launch_bounds__(256) void k_scatter(const void* __restrict__ ei, const int* __restrict__ flags,
                                                 int* __restrict__ cursors, int* __restrict__ ssort){
    int i = blockIdx.x * 256 + threadIdx.x;
    if (i >= ET) return;
    int is64 = flags[0];
    int s, d;
    if (i < N_EDGES){
        if (is64){
            s = (int)((const long long*)ei)[i];
            d = (int)((const long long*)ei)[N_EDGES + i];
        } else {
            s = ((const int*)ei)[i];
            d = ((const int*)ei)[N_EDGES + i];
        }
    } else { s = i - N_EDGES; d = s; }
    int pos = atomicAdd(&cursors[d], 1);
    ssort[pos] = s;
}

/* ---------------- per-head bound for layer 2 ---------------- */
__global__ __launch_bounds__(256) void k_bound(const float* __restrict__ alS2, const float* __restrict__ alD2,
                                               uint32* __restrict__ bnd){
    int g = blockIdx.x * 256 + threadIdx.x;
    int lane = threadIdx.x & 63;
    float ms = 0.f, md = 0.f;
    for (int i = g; i < 80000; i += 10240){ ms = fmaxf(ms, alS2[i]); md = fmaxf(md, alD2[i]); }
    #pragma unroll
    for (int o = 8; o < 64; o <<= 1){
        ms = fmaxf(ms, __shfl_xor(ms, o, 64));
        md = fmaxf(md, __shfl_xor(md, o, 64));
    }
    if (lane < 8){
        atomicMax(&bnd[16 + lane], __float_as_uint(ms));
        atomicMax(&bnd[24 + lane], __float_as_uint(md));
    }
}

/* ---------------- fused segment-softmax + aggregate + bias + relu (v4) ----------------
   Single pass with per-head global upper bound B (see R7). 2 nodes/block,
   2 waves/node, lane owns 8 channels, x8-unrolled gathers. */
__global__ __launch_bounds__(256) void k_gat_agg(const ushort_t* __restrict__ H, const float* __restrict__ alS,
                                                 const float* __restrict__ alD, const uint32* __restrict__ bnd,
                                                 int bo, const int* __restrict__ offs,
                                                 const int* __restrict__ srcs, const float* __restrict__ bias,
                                                 ushort_t* __restrict__ out){
    int tid = threadIdx.x;
    int wv = tid >> 6, lane = tid & 63;
    int n = blockIdx.x * 2 + (wv >> 1);
    int half = wv & 1;
    int beg = offs[n], end = offs[n+1];
    int head = half*4 + (lane >> 4);
    float ad = alD[n*HEADS + head];
    float B = __uint_as_float(bnd[bo + head]) + __uint_as_float(bnd[bo + 8 + head]);

    int ch0 = half*512 + lane*8;
    const ushort_t* Hc = H + ch0;
    float z = 0.f;
    float c0=0.f,c1=0.f,c2=0.f,c3=0.f,c4=0.f,c5=0.f,c6=0.f,c7=0.f;
    for (int c = beg; c < end; c += 64){
        int cn = min(64, end - c);
        int sreg = (lane < cn) ? srcs[c + lane] : 0;
        int j = 0;
        for (; j + 8 <= cn; j += 8){
            int s[8]; uint4 u[8]; float e[8];
            #pragma unroll
            for (int q = 0; q < 8; q++) s[q] = __shfl(sreg, j + q, 64);
            #pragma unroll
            for (int q = 0; q < 8; q++) u[q] = *(const uint4*)(Hc + (size_t)s[q]*HT);
            #pragma unroll
            for (int q = 0; q < 8; q++) e[q] = alS[s[q]*HEADS + head];
            #pragma unroll
            for (int q = 0; q < 8; q++){
                float v = e[q] + ad;
                v = v > 0.f ? v : NEG*v;
                float w = __expf(v - B);
                z += w;
                float f0,f1,f2,f3,f4,f5,f6,f7;
                unpack2(u[q].x,f0,f1); unpack2(u[q].y,f2,f3);
                unpack2(u[q].z,f4,f5); unpack2(u[q].w,f6,f7);
                c0+=w*f0; c1+=w*f1; c2+=w*f2; c3+=w*f3;
                c4+=w*f4; c5+=w*f5; c6+=w*f6; c7+=w*f7;
            }
        }
        for (; j < cn; j++){
            int s0 = __shfl(sreg, j, 64);
            uint4 u0 = *(const uint4*)(Hc + (size_t)s0*HT);
            float v = alS[s0*HEADS + head] + ad;
            v = v > 0.f ? v : NEG*v;
            float w = __expf(v - B);
            z += w;
            float f0,f1,f2,f3,f4,f5,f6,f7;
            unpack2(u0.x,f0,f1); unpack2(u0.y,f2,f3); unpack2(u0.z,f4,f5); unpack2(u0.w,f6,f7);
            c0+=w*f0; c1+=w*f1; c2+=w*f2; c3+=w*f3;
            c4+=w*f4; c5+=w*f5; c6+=w*f6; c7+=w*f7;
        }
    }
    float inv = 1.f / z;
    float4 b0 = *(const float4*)(bias + ch0);
    float4 b1 = *(const float4*)(bias + ch0 + 4);
    c0 = fmaxf(c0*inv + b0.x, 0.f); c1 = fmaxf(c1*inv + b0.y, 0.f);
    c2 = fmaxf(c2*inv + b0.z, 0.f); c3 = fmaxf(c3*inv + b0.w, 0.f);
    c4 = fmaxf(c4*inv + b1.x, 0.f); c5 = fmaxf(c5*inv + b1.y, 0.f);
    c6 = fmaxf(c6*inv + b1.z, 0.f); c7 = fmaxf(c7*inv + b1.w, 0.f);
    uint4 o;
    o.x = (uint32)f2bf(c0) | ((uint32)f2bf(c1) << 16);
    o.y = (uint32)f2bf(c2) | ((uint32)f2bf(c3) << 16);
    o.z = (uint32)f2bf(c4) | ((uint32)f2bf(c5) << 16);
    o.w = (uint32)f2bf(c6) | ((uint32)f2bf(c7) << 16);
    *(uint4*)(out + (size_t)n*HT + ch0) = o;
}

/* ---------------- layer-2 GEMM: bf16 MFMA, 128x64 tiles, BK=64, XOR-swizzled LDS ---------------- */
__global__ __launch_bounds__(256) void k_gemm2(const ushort_t* __restrict__ A, const ushort_t* __restrict__ BT,
                                               ushort_t* __restrict__ C,
                                               const float* __restrict__ aS, const float* __restrict__ aD,
                                               float* __restrict__ alS2, float* __restrict__ alD2){
    __shared__ ushort_t lA[128*64];   /* 16 KB */
    __shared__ ushort_t lB[64*64];    /* 8 KB */
    int bn = blockIdx.x, bm = blockIdx.y;
    int tid = threadIdx.x;
    int lane = tid & 63;
    int wave = tid >> 6;
    int wm = wave * 32;
    int lm = lane & 15, kg = lane >> 4;
    int swz = lm & 7;
    f32x4 acc[2][4];
    #pragma unroll
    for (int i = 0; i < 2; i++)
        #pragma unroll
        for (int j = 0; j < 4; j++) acc[i][j] = (f32x4)0.0f;

    int rowA0 = bm * 128, rowB0 = bn * 64;
    for (int k0 = 0; k0 < 1024; k0 += 64){
        #pragma unroll
        for (int it = 0; it < 4; ++it){
            int s = tid + it*256;
            int r = s >> 3, q = s & 7;
            int ra = rowA0 + r; if (ra > N_NODES-1) ra = N_NODES-1;
            gload_lds16(A + (size_t)ra*1024 + k0 + (q ^ (r & 7))*8, lA + s*8);
        }
        #pragma unroll
        for (int it = 0; it < 2; ++it){
            int s = tid + it*256;
            int r = s >> 3, q = s & 7;
            gload_lds16(BT + (size_t)(rowB0 + r)*1024 + k0 + (q ^ (r & 7))*8, lB + s*8);
        }
        __syncthreads();
        #pragma unroll
        for (int kh = 0; kh < 2; kh++){
            bf16x8 af[2], bfr[4];
            int qb = kh*4 + kg;
            int qp = (qb ^ swz) * 8;
            #pragma unroll
            for (int mt = 0; mt < 2; mt++) af[mt]  = *(const bf16x8*)(lA + (wm + mt*16 + lm)*64 + qp);
            #pragma unroll
            for (int nt = 0; nt < 4; nt++) bfr[nt] = *(const bf16x8*)(lB + (nt*16 + lm)*64 + qp);
            #pragma unroll
            for (int mt = 0; mt < 2; mt++)
                #pragma unroll
                for (int nt = 0; nt < 4; nt++)
                    acc[mt][nt] = __builtin_amdgcn_mfma_f32_16x16x32_bf16(af[mt], bfr[nt], acc[mt][nt], 0, 0, 0);
        }
        __syncthreads();
    }
    #pragma unroll
    for (int mt = 0; mt < 2; mt++){
        int row_base = bm*128 + wm + mt*16 + kg*4;
        #pragma unroll
        for (int nt = 0; nt < 4; nt++){
            int col = bn*64 + nt*16 + lm;
            #pragma unroll
            for (int r = 0; r < 4; r++){
                int row = row_base + r;
                if (row < N_NODES) C[(size_t)row*HT + col] = f2bf(acc[mt][nt][r]);
            }
        }
    }
    /* partial attention dots over this block's 64 cols (head = bn>>1) */
    int head = bn >> 1;
    float as_l[4], ad_l[4];
    #pragma unroll
    for (int nt = 0; nt < 4; nt++){
        as_l[nt] = aS[bn*64 + nt*16 + lm];
        ad_l[nt] = aD[bn*64 + nt*16 + lm];
    }
    #pragma unroll
    for (int mt = 0; mt < 2; mt++){
        #pragma unroll
        for (int r = 0; r < 4; r++){
            float ps = acc[mt][0][r]*as_l[0] + acc[mt][1][r]*as_l[1]
                     + acc[mt][2][r]*as_l[2] + acc[mt][3][r]*as_l[3];
            float pd = acc[mt][0][r]*ad_l[0] + acc[mt][1][r]*ad_l[1]
                     + acc[mt][2][r]*ad_l[2] + acc[mt][3][r]*ad_l[3];
            #pragma unroll
            for (int o = 1; o < 16; o <<= 1){ ps += __shfl_xor(ps, o, 64); pd += __shfl_xor(pd, o, 64); }
            if (lm == 0){
                int row = bm*128 + wm + mt*16 + kg*4 + r;
                if (row < N_NODES){
                    atomicAdd(&alS2[row*HEADS + head], ps);
                    atomicAdd(&alD2[row*HEADS + head], pd);
                }
            }
        }
    }
}

/* ---------------- layer-3 GEMM: wave-per-node, W3 in registers ---------------- */
__global__ __launch_bounds__(256) void k_gemm3(const ushort_t* __restrict__ A, const float* __restrict__ W3,
                                               const float* __restrict__ s3,
                                               float* __restrict__ h3, float* __restrict__ al3s, float* __restrict__ al3d){
    int tid = threadIdx.x;
    int lane = tid & 63, wave = tid >> 6;
    int n = blockIdx.x * 4 + wave;
    if (n >= N_NODES) return;
    float4 w3r[16];
    #pragma unroll
    for (int j = 0; j < 16; j++) w3r[j] = ((const float4*)W3)[lane*16 + j];
    const uint4* ap = (const uint4*)(A + (size_t)n*HT + lane*16);
    uint4 u0 = ap[0], u1 = ap[1];
    uint32 uu[8] = {u0.x,u0.y,u0.z,u0.w,u1.x,u1.y,u1.z,u1.w};
    float acc0=0.f, acc1=0.f, acc2=0.f, acc3=0.f;
    #pragma unroll
    for (int p = 0; p < 8; p++){
        float lo, hi;
        unpack2(uu[p], lo, hi);
        float4 wl = w3r[p*2], wh = w3r[p*2+1];
        acc0 += lo*wl.x + hi*wh.x;
        acc1 += lo*wl.y + hi*wh.y;
        acc2 += lo*wl.z + hi*wh.z;
        acc3 += lo*wl.w + hi*wh.w;
    }
    #pragma unroll
    for (int o = 32; o; o >>= 1){
        acc0 += __shfl_xor(acc0, o, 64); acc1 += __shfl_xor(acc1, o, 64);
        acc2 += __shfl_xor(acc2, o, 64); acc3 += __shfl_xor(acc3, o, 64);
    }
    if (lane == 0){
        *(float4*)(h3 + n*4) = make_float4(acc0, acc1, acc2, acc3);
        al3s[n] = acc0*s3[0] + acc1*s3[1] + acc2*s3[2] + acc3*s3[3];
        al3d[n] = acc0*s3[16] + acc1*s3[17] + acc2*s3[18] + acc3*s3[19];
    }
}

/* ---------------- layer-3 attention aggregate: wave-per-node ---------------- */
__global__ __launch_bounds__(256) void k_gat_agg3(const float* __restrict__ h3, const float* __restrict__ al3s,
                                                  const float* __restrict__ al3d, const int* __restrict__ offs,
                                                  const int* __restrict__ srcs, const float* __restrict__ b3,
                                                  const int* __restrict__ flags, void* __restrict__ out){
    int tid = threadIdx.x;
    int l = tid & 63, wave = tid >> 6;
    int n = blockIdx.x * 4 + wave;
    if (n >= N_NODES) return;
    int beg = offs[n], end = offs[n+1];
    float ad = al3d[n];
    float m = -1e30f;
    for (int e = beg + l; e < end; e += 64){
        float v = al3s[srcs[e]] + ad; v = v > 0.f ? v : NEG*v;
        m = fmaxf(m, v);
    }
    #pragma unroll
    for (int o = 32; o; o >>= 1) m = fmaxf(m, __shfl_xor(m, o, 64));
    float z = 0.f;
    for (int e = beg + l; e < end; e += 64){
        float v = al3s[srcs[e]] + ad; v = v > 0.f ? v : NEG*v;
        z += __expf(v - m);
    }
    #pragma unroll
    for (int o = 32; o; o >>= 1) z += __shfl_xor(z, o, 64);
    float inv = 1.f / (z + 1e-16f);
    float a0=0.f, a1=0.f, a2=0.f, a3=0.f;
    for (int e = beg + l; e < end; e += 64){
        int s = srcs[e];
        float v = al3s[s] + ad; v = v > 0.f ? v : NEG*v;
        float w = __expf(v - m) * inv;
        float4 hv = *(const float4*)(h3 + s*4);
        a0 += w*hv.x; a1 += w*hv.y; a2 += w*hv.z; a3 += w*hv.w;
    }
    #pragma unroll
    for (int o = 32; o; o >>= 1){
        a0 += __shfl_xor(a0, o, 64); a1 += __shfl_xor(a1, o, 64);
        a2 += __shfl_xor(a2, o, 64); a3 += __shfl_xor(a3, o, 64);
    }
    if (l == 0){
        float r0 = fmaxf(a0 + b3[0], 0.f);
        float r1 = fmaxf(a1 + b3[1], 0.f);
        float r2 = fmaxf(a2 + b3[2], 0.f);
        float r3 = fmaxf(a3 + b3[3], 0.f);
        if (flags[1]){
            float* o4 = (float*)out;
            o4[n*4+0]=r0; o4[n*4+1]=r1; o4[n*4+2]=r2; o4[n*4+3]=r3;
        } else {
            ushort_t* o2 = (ushort_t*)out;
            o2[n*4+0]=f2bf(r0); o2[n*4+1]=f2bf(r1); o2[n*4+2]=f2bf(r2); o2[n*4+3]=f2bf(r3);
        }
    }
}

extern "C" void kernel_launch(void* const* d_in, const int* in_sizes, int n_in,
                              void* d_out, int out_size, void* d_ws, size_t ws_size,
                              hipStream_t stream){
    const void* x   = d_in[0];
    const void* ei  = d_in[1];
    const void* W1  = d_in[2];
    const void* W2  = d_in[6];
    const void* W3  = d_in[10];

    char* ws = (char*)d_ws;
    int* flags     = (int*)(ws + O_FLAG);
    uint32* bnd    = (uint32*)(ws + O_BND);
    int* bsum      = (int*)(ws + O_BSUM);
    int* counts    = (int*)(ws + O_COUNTS);   /* also cursors */
    int* offs      = (int*)(ws + O_OFFS);
    int* ssort     = (int*)(ws + O_SSORT);
    float* alS1    = (float*)(ws + O_ALS1);
    float* alD1    = (float*)(ws + O_ALD1);
    float* alS2    = (float*)(ws + O_ALS2);
    float* alD2    = (float*)(ws + O_ALD2);
    float* al3s    = (float*)(ws + O_AL3S);
    float* al3d    = (float*)(ws + O_AL3D);
    float* h3      = (float*)(ws + O_H3);
    float* wvecF   = (float*)(ws + O_WVEC);
    float* W3F     = (float*)(ws + O_W3F);
    float* s3F     = (float*)(ws + O_S3F);
    ushort_t* W2T  = (ushort_t*)(ws + O_W2T);
    ushort_t* bufA = (ushort_t*)(ws + O_BUFA);
    ushort_t* bufB = (ushort_t*)(ws + O_BUFB);

    const int EB = (ET + 255) / 256;

    CvtArgs ca;
    ca.vsrc[0]=d_in[3];  ca.vsrc[1]=d_in[4];  ca.vsrc[2]=d_in[5];
    ca.vsrc[3]=d_in[7];  ca.vsrc[4]=d_in[8];  ca.vsrc[5]=d_in[9];
    ca.w3src = W3;
    ca.s3src[0]=d_in[11]; ca.s3src[1]=d_in[12]; ca.s3src[2]=d_in[13];

    k_setup<<<1202, 256, 0, stream>>>(ca, W2, (const uint32*)W1, (const int*)ei, flags,
                                      wvecF, W3F, s3F, counts, alS2, alD2, bnd, W2T);
    /* extract/hist (665 blocks) ∥ layer-1 gemm+dots (512 blocks) */
    k_exgemm1<<<1177, 256, 0, stream>>>(ei, x, W1, flags, wvecF, counts, bufA, alS1, alD1, bnd);
    k_scan_a<<<40, 256, 0, stream>>>(counts, bsum);
    k_scan_b<<<40, 256, 0, stream>>>(counts, bsum, offs);
    k_scatter<<<EB, 256, 0, stream>>>(ei, flags, counts, ssort);

    /* layer 1 aggregate */
    k_gat_agg<<<5000, 256, 0, stream>>>(bufA, alS1, alD1, bnd, 0, offs, ssort, wvecF + 2*1024, bufB);

    /* layer 2 */
    k_gemm2<<<dim3(16, 79), 256, 0, stream>>>(bufB, W2T, bufA, wvecF + 3*1024, wvecF + 4*1024, alS2, alD2);
    k_bound<<<40, 256, 0, stream>>>(alS2, alD2, bnd);
    k_gat_agg<<<5000, 256, 0, stream>>>(bufA, alS2, alD2, bnd, 16, offs, ssort, wvecF + 5*1024, bufB);

    /* layer 3 */
    k_gemm3<<<2500, 256, 0, stream>>>(bufB, W3F, s3F, h3, al3s, al3d);
    k_gat_agg3<<<2500, 256, 0, stream>>>(h3, al3s, al3d, offs, ssort, s3F + 32, flags, d_out);
}

// Round 10
// 330.922 us; speedup vs baseline: 1.9883x; 1.0124x over previous
//
#include <hip/hip_runtime.h>

typedef unsigned short ushort_t;
typedef unsigned int uint32;

#define N_NODES 10000
#define N_EDGES 160000
#define ET (N_NODES + N_EDGES)   /* 170000 edges incl self-loops */
#define HT 1024                  /* heads * hid */
#define HEADS 8
#define NEG 0.2f

/* ---- ws layout (bytes). counts doubles as scatter cursors; layer-3 arrays
   overlay alS2/alD2 (free after layer-2 agg). */
#define O_FLAG     0
#define O_BND      64                       /* 32 uints: B1S[8] B1D[8] B2S[8] B2D[8] */
#define O_BSUM     192                      /* 40 ints scan partials */
#define O_COUNTS   512                      /* 40192; also cursors */
#define O_OFFS     (O_COUNTS + 40192)
#define O_SSORT    (O_OFFS + 40192)         /* 680192 */
#define O_ALS1     (O_SSORT + 680192)       /* 320000 */
#define O_ALD1     (O_ALS1 + 320000)
#define O_ALS2     (O_ALD1 + 320000)        /* 320000, zeroed, atomic dots */
#define O_ALD2     (O_ALS2 + 320000)
#define O_AL3S     O_ALS2                   /* overlay: layer-3 phase only */
#define O_AL3D     (O_ALS2 + 40192)
#define O_H3       (O_ALS2 + 80384)
#define O_WVEC     (O_ALD2 + 320000)        /* 6x1024 floats */
#define O_W3F      (O_WVEC + 24576)
#define O_S3F      (O_W3F + 16384)
#define O_W2T      (O_S3F + 768)            /* bf16 [1024,1024] transposed */
#define O_BUFA     (O_W2T + 2097152)
#define O_BUFB     (O_BUFA + 20480000)

__device__ __forceinline__ float bf2f(ushort_t u){ return __uint_as_float(((uint32)u) << 16); }
__device__ __forceinline__ ushort_t f2bf(float f){
    uint32 x = __float_as_uint(f);
    return (ushort_t)((x + 0x7fffu + ((x >> 16) & 1u)) >> 16);
}
__device__ __forceinline__ void unpack2(uint32 u, float& lo, float& hi){
    lo = __uint_as_float(u << 16);
    hi = __uint_as_float(u & 0xffff0000u);
}

typedef __bf16 bf16x8 __attribute__((ext_vector_type(8)));
typedef float  f32x4  __attribute__((ext_vector_type(4)));

typedef const __attribute__((address_space(1))) uint32* gas1_u32;
typedef       __attribute__((address_space(3))) uint32* las3_u32;

__device__ __forceinline__ void gload_lds16(const void* g, void* l){
    __builtin_amdgcn_global_load_lds((gas1_u32)g, (las3_u32)l, 16, 0, 0);
}

/* dtype probes (R1/R2 analysis): bf16 low-element exponent concentrates near
   127; fp32 low 16 bits are uniform mantissa bits. */
__device__ __forceinline__ int probe_f32(const uint32* __restrict__ w){
    int cnt = 0;
    for (int i = 0; i < 256; i++){
        uint32 e = (w[i] >> 7) & 0xffu;
        cnt += (e >= 64u && e <= 160u) ? 1 : 0;
    }
    return (cnt > 200) ? 0 : 1;
}
__device__ __forceinline__ int probe_edge64(const int* __restrict__ ei){
    int nz = 0;
    for (int i = 0; i < 128; i++) nz |= ei[2*i + 1];
    return (nz == 0) ? 1 : 0;
}

__device__ __forceinline__ float cvt1(const void* p, int i, int f32){
    return f32 ? ((const float*)p)[i] : bf2f(((const ushort_t*)p)[i]);
}

/* ---------------- k_pre: flags + small conversions + counts/bnd zero (12 blocks) ---------------- */
struct CvtArgs {
    const void* vsrc[6];   /* as1,ad1,b1,as2,ad2,b2 */
    const void* w3src;
    const void* s3src[3];  /* as3,ad3,b3 */
};

__global__ __launch_bounds__(256) void k_pre(CvtArgs a, const uint32* __restrict__ w1raw,
                                             const int* __restrict__ eiraw,
                                             int* __restrict__ flags,
                                             float* __restrict__ wvecF, float* __restrict__ W3F,
                                             float* __restrict__ s3F,
                                             int* __restrict__ counts, uint32* __restrict__ bnd){
    int b = blockIdx.x, tid = threadIdx.x;
    int f32 = probe_f32(w1raw);
    if (b == 0){
        if (tid < 32) bnd[tid] = 0;
        if (tid == 32) flags[0] = probe_edge64(eiraw);
        if (tid == 33) flags[1] = f32;
        if (tid >= 64 && tid < 76){
            int off = tid - 64;
            s3F[(off >> 2) * 16 + (off & 3)] = cvt1(a.s3src[off >> 2], off & 3, f32);
        }
    } else if (b <= 6){
        int g = tid * 4;
        #pragma unroll
        for (int j = 0; j < 4; j++) wvecF[(b-1)*1024 + g + j] = cvt1(a.vsrc[b-1], g + j, f32);
    } else if (b <= 10){
        int g = (b - 7) * 1024 + tid * 4;
        #pragma unroll
        for (int j = 0; j < 4; j++) W3F[g + j] = cvt1(a.w3src, g + j, f32);
    } else {
        for (int i = tid * 4; i < N_NODES; i += 1024){
            #pragma unroll
            for (int j = 0; j < 4; j++) if (i + j < N_NODES) counts[i + j] = 0;
        }
    }
}

/* ---------------- k_mega1: extract/hist [0,665) ∥ layer-1 GEMM+dots [665,1177)
   ∥ W2 transpose [1177,1689) ∥ alS2/alD2 zero [1689,1846). All depend only on
   k_pre. W1 staged as bf16 (28KB LDS -> 5 blocks/CU; R9's 56KB fp32 stage was
   the 50µs occupancy killer). */
__global__ __launch_bounds__(256) void k_mega1(const void* __restrict__ ei, const void* __restrict__ x,
                                               const void* __restrict__ W1, const void* __restrict__ W2,
                                               const int* __restrict__ flags,
                                               const float* __restrict__ wvecF,
                                               int* __restrict__ counts,
                                               ushort_t* __restrict__ h1,
                                               float* __restrict__ alS, float* __restrict__ alD,
                                               uint32* __restrict__ bnd,
                                               ushort_t* __restrict__ W2T,
                                               float* __restrict__ alS2, float* __restrict__ alD2){
    __shared__ ushort_t lsh[14336];   /* 28KB: W1-bf16 stage / transpose tiles */
    __shared__ uint32 smax[16];
    int bid = blockIdx.x, tid = threadIdx.x;
    if (bid < 665){
        /* extract + histogram */
        int i = bid * 256 + tid;
        int is64 = flags[0];
        int d = -1;
        if (i < N_EDGES){
            d = is64 ? (int)((const long long*)ei)[N_EDGES + i] : ((const int*)ei)[N_EDGES + i];
        } else if (i < ET){
            d = i - N_EDGES;
        }
        if (d >= 0) atomicAdd(&counts[d], 1);
        return;
    }
    if (bid < 1177){
        /* layer-1 GEMM + attention dots + per-head bound B1 */
        int gb = bid - 665;             /* 0..511 */
        int f32 = flags[1];
        if (tid < 16) smax[tid] = 0;
        if (f32){
            for (int i = tid; i < 14336; i += 256) lsh[i] = f2bf(((const float*)W1)[i]);
        } else {
            for (int i = tid * 8; i < 14336; i += 2048)
                *(uint4*)(lsh + i) = *(const uint4*)((const ushort_t*)W1 + i);
        }
        __syncthreads();
        int c0 = tid * 4;
        float4 sv = *(const float4*)(wvecF + c0);
        float4 dv = *(const float4*)(wvecF + 1024 + c0);
        int head = tid >> 5, l32 = tid & 31;
        #pragma unroll 1
        for (int n = gb; n < N_NODES; n += 512){
            float a0=0.f, a1=0.f, a2=0.f, a3=0.f;
            #pragma unroll
            for (int k = 0; k < 14; k++){
                float xv = f32 ? ((const float*)x)[n*14 + k] : bf2f(((const ushort_t*)x)[n*14 + k]);
                uint2 u = *(const uint2*)(lsh + k*HT + c0);
                float w0,w1,w2,w3;
                unpack2(u.x, w0, w1); unpack2(u.y, w2, w3);
                a0 += xv*w0; a1 += xv*w1; a2 += xv*w2; a3 += xv*w3;
            }
            uint2 o;
            o.x = (uint32)f2bf(a0) | ((uint32)f2bf(a1) << 16);
            o.y = (uint32)f2bf(a2) | ((uint32)f2bf(a3) << 16);
            *(uint2*)(h1 + (size_t)n*HT + c0) = o;
            float h0,h1v,h2,h3v;
            unpack2(o.x, h0, h1v); unpack2(o.y, h2, h3v);
            float s = h0*sv.x + h1v*sv.y + h2*sv.z + h3v*sv.w;
            float d = h0*dv.x + h1v*dv.y + h2*dv.z + h3v*dv.w;
            #pragma unroll
            for (int of = 16; of; of >>= 1){ s += __shfl_xor(s, of, 32); d += __shfl_xor(d, of, 32); }
            if (l32 == 0){
                alS[n*HEADS + head] = s; alD[n*HEADS + head] = d;
                atomicMax(&smax[head],     __float_as_uint(fmaxf(s, 0.f)));
                atomicMax(&smax[8 + head], __float_as_uint(fmaxf(d, 0.f)));
            }
        }
        __syncthreads();
        if (tid < 16) atomicMax(&bnd[tid], smax[tid]);
        return;
    }
    if (bid < 1689){
        /* W2 transpose -> bf16 [N,K], 2 tiles/block */
        int f32 = flags[1];
        ushort_t (*tile)[33] = (ushort_t (*)[33])lsh;
        int cx = tid & 31, ry = (tid >> 5) * 4;
        int t2 = (bid - 1177) * 2;
        #pragma unroll 1
        for (int tt = 0; tt < 2; tt++){
            int t = t2 + tt;
            int bx = t & 31, by = t >> 5;
            __syncthreads();
            #pragma unroll
            for (int r = 0; r < 4; r++){
                size_t idx = (size_t)(by*32 + ry + r)*1024 + bx*32 + cx;
                tile[ry + r][cx] = f32 ? f2bf(((const float*)W2)[idx]) : ((const ushort_t*)W2)[idx];
            }
            __syncthreads();
            #pragma unroll
            for (int r = 0; r < 4; r++)
                W2T[(size_t)(bx*32 + ry + r)*1024 + by*32 + cx] = tile[cx][ry + r];
        }
        return;
    }
    /* alS2/alD2 zero */
    int g = (bid - 1689) * 1024 + tid * 4;
    if (g < 80000){ *(float4*)(alS2 + g) = make_float4(0,0,0,0); }
    else if (g < 160000){ *(float4*)(alD2 + g - 80000) = make_float4(0,0,0,0); }
}

/* ---------------- parallel scan: 40-block sums, then 40-block scan ---------------- */
__global__ __launch_bounds__(256) void k_scan_a(const int* __restrict__ counts, int* __restrict__ bsum){
    __shared__ int ws[4];
    int b = blockIdx.x, tid = threadIdx.x;
    int i = b * 256 + tid;
    int v = (i < N_NODES) ? counts[i] : 0;
    int lane = tid & 63, wid = tid >> 6;
    #pragma unroll
    for (int o = 32; o; o >>= 1) v += __shfl_xor(v, o, 64);
    if (lane == 0) ws[wid] = v;
    __syncthreads();
    if (tid == 0) bsum[b] = ws[0] + ws[1] + ws[2] + ws[3];
}

__global__ __launch_bounds__(256) void k_scan_b(int* __restrict__ counts, const int* __restrict__ bsum,
                                                int* __restrict__ offs){
    __shared__ int ws[4];
    int b = blockIdx.x, tid = threadIdx.x;
    int i = b * 256 + tid;
    int v = (i < N_NODES) ? counts[i] : 0;
    int base = 0;
    #pragma unroll 1
    for (int j = 0; j < b; j++) base += bsum[j];
    int lane = tid & 63, wid = tid >> 6;
    int inc = v;
    #pragma unroll
    for (int d = 1; d < 64; d <<= 1){
        int t = __shfl_up(inc, d, 64);
        if (lane >= d) inc += t;
    }
    if (lane == 63) ws[wid] = inc;
    __syncthreads();
    int wpre = 0;
    #pragma unroll
    for (int j = 0; j < 4; j++) if (j < wid) wpre += ws[j];
    int excl = base + wpre + inc - v;
    if (i < N_NODES){ offs[i] = excl; counts[i] = excl; }  /* counts becomes cursors */
    if (i == N_NODES) offs[i] = excl;                      /* == ET */
}

__global__ __launch_bounds__(256) void k_scatter(const void* __restrict__ ei, const int* __restrict__ flags,
                                                 int* __restrict__ cursors, int* __restrict__ ssort){
    int i = blockIdx.x * 256 + threadIdx.x;
    if (i >= ET) return;
    int is64 = flags[0];
    int s, d;
    if (i < N_EDGES){
        if (is64){
            s = (int)((const long long*)ei)[i];
            d = (int)((const long long*)ei)[N_EDGES + i];
        } else {
            s = ((const int*)ei)[i];
            d = ((const int*)ei)[N_EDGES + i];
        }
    } else { s = i - N_EDGES; d = s; }
    int pos = atomicAdd(&cursors[d], 1);
    ssort[pos] = s;
}

/* ---------------- per-head bound for layer 2 ---------------- */
__global__ __launch_bounds__(256) void k_bound(const float* __restrict__ alS2, const float* __restrict__ alD2,
                                               uint32* __restrict__ bnd){
    int g = blockIdx.x * 256 + threadIdx.x;
    int lane = threadIdx.x & 63;
    float ms = 0.f, md = 0.f;
    for (int i = g; i < 80000; i += 10240){ ms = fmaxf(ms, alS2[i]); md = fmaxf(md, alD2[i]); }
    #pragma unroll
    for (int o = 8; o < 64; o <<= 1){
        ms = fmaxf(ms, __shfl_xor(ms, o, 64));
        md = fmaxf(md, __shfl_xor(md, o, 64));
    }
    if (lane < 8){
        atomicMax(&bnd[16 + lane], __float_as_uint(ms));
        atomicMax(&bnd[24 + lane], __float_as_uint(md));
    }
}

/* ---------------- fused segment-softmax + aggregate + bias + relu (v4) ----------------
   Single pass with per-head global upper bound B (see R7). 2 nodes/block,
   2 waves/node, lane owns 8 channels, x8-unrolled gathers. Near load-issue floor. */
__global__ __launch_bounds__(256) void k_gat_agg(const ushort_t* __restrict__ H, const float* __restrict__ alS,
                                                 const float* __restrict__ alD, const uint32* __restrict__ bnd,
                                                 int bo, const int* __restrict__ offs,
                                                 const int* __restrict__ srcs, const float* __restrict__ bias,
                                                 ushort_t* __restrict__ out){
    int tid = threadIdx.x;
    int wv = tid >> 6, lane = tid & 63;
    int n = blockIdx.x * 2 + (wv >> 1);
    int half = wv & 1;
    int beg = offs[n], end = offs[n+1];
    int head = half*4 + (lane >> 4);
    float ad = alD[n*HEADS + head];
    float B = __uint_as_float(bnd[bo + head]) + __uint_as_float(bnd[bo + 8 + head]);

    int ch0 = half*512 + lane*8;
    const ushort_t* Hc = H + ch0;
    float z = 0.f;
    float c0=0.f,c1=0.f,c2=0.f,c3=0.f,c4=0.f,c5=0.f,c6=0.f,c7=0.f;
    for (int c = beg; c < end; c += 64){
        int cn = min(64, end - c);
        int sreg = (lane < cn) ? srcs[c + lane] : 0;
        int j = 0;
        for (; j + 8 <= cn; j += 8){
            int s[8]; uint4 u[8]; float e[8];
            #pragma unroll
            for (int q = 0; q < 8; q++) s[q] = __shfl(sreg, j + q, 64);
            #pragma unroll
            for (int q = 0; q < 8; q++) u[q] = *(const uint4*)(Hc + (size_t)s[q]*HT);
            #pragma unroll
            for (int q = 0; q < 8; q++) e[q] = alS[s[q]*HEADS + head];
            #pragma unroll
            for (int q = 0; q < 8; q++){
                float v = e[q] + ad;
                v = v > 0.f ? v : NEG*v;
                float w = __expf(v - B);
                z += w;
                float f0,f1,f2,f3,f4,f5,f6,f7;
                unpack2(u[q].x,f0,f1); unpack2(u[q].y,f2,f3);
                unpack2(u[q].z,f4,f5); unpack2(u[q].w,f6,f7);
                c0+=w*f0; c1+=w*f1; c2+=w*f2; c3+=w*f3;
                c4+=w*f4; c5+=w*f5; c6+=w*f6; c7+=w*f7;
            }
        }
        for (; j < cn; j++){
            int s0 = __shfl(sreg, j, 64);
            uint4 u0 = *(const uint4*)(Hc + (size_t)s0*HT);
            float v = alS[s0*HEADS + head] + ad;
            v = v > 0.f ? v : NEG*v;
            float w = __expf(v - B);
            z += w;
            float f0,f1,f2,f3,f4,f5,f6,f7;
            unpack2(u0.x,f0,f1); unpack2(u0.y,f2,f3); unpack2(u0.z,f4,f5); unpack2(u0.w,f6,f7);
            c0+=w*f0; c1+=w*f1; c2+=w*f2; c3+=w*f3;
            c4+=w*f4; c5+=w*f5; c6+=w*f6; c7+=w*f7;
        }
    }
    float inv = 1.f / z;
    float4 b0 = *(const float4*)(bias + ch0);
    float4 b1 = *(const float4*)(bias + ch0 + 4);
    c0 = fmaxf(c0*inv + b0.x, 0.f); c1 = fmaxf(c1*inv + b0.y, 0.f);
    c2 = fmaxf(c2*inv + b0.z, 0.f); c3 = fmaxf(c3*inv + b0.w, 0.f);
    c4 = fmaxf(c4*inv + b1.x, 0.f); c5 = fmaxf(c5*inv + b1.y, 0.f);
    c6 = fmaxf(c6*inv + b1.z, 0.f); c7 = fmaxf(c7*inv + b1.w, 0.f);
    uint4 o;
    o.x = (uint32)f2bf(c0) | ((uint32)f2bf(c1) << 16);
    o.y = (uint32)f2bf(c2) | ((uint32)f2bf(c3) << 16);
    o.z = (uint32)f2bf(c4) | ((uint32)f2bf(c5) << 16);
    o.w = (uint32)f2bf(c6) | ((uint32)f2bf(c7) << 16);
    *(uint4*)(out + (size_t)n*HT + ch0) = o;
}

/* ---------------- layer-2 GEMM: bf16 MFMA, 128x64 tiles, BK=64, XOR-swizzled LDS ---------------- */
__global__ __launch_bounds__(256) void k_gemm2(const ushort_t* __restrict__ A, const ushort_t* __restrict__ BT,
                                               ushort_t* __restrict__ C,
                                               const float* __restrict__ aS, const float* __restrict__ aD,
                                               float* __restrict__ alS2, float* __restrict__ alD2){
    __shared__ ushort_t lA[128*64];   /* 16 KB */
    __shared__ ushort_t lB[64*64];    /* 8 KB */
    int bn = blockIdx.x, bm = blockIdx.y;
    int tid = threadIdx.x;
    int lane = tid & 63;
    int wave = tid >> 6;
    int wm = wave * 32;
    int lm = lane & 15, kg = lane >> 4;
    int swz = lm & 7;
    f32x4 acc[2][4];
    #pragma unroll
    for (int i = 0; i < 2; i++)
        #pragma unroll
        for (int j = 0; j < 4; j++) acc[i][j] = (f32x4)0.0f;

    int rowA0 = bm * 128, rowB0 = bn * 64;
    for (int k0 = 0; k0 < 1024; k0 += 64){
        #pragma unroll
        for (int it = 0; it < 4; ++it){
            int s = tid + it*256;
            int r = s >> 3, q = s & 7;
            int ra = rowA0 + r; if (ra > N_NODES-1) ra = N_NODES-1;
            gload_lds16(A + (size_t)ra*1024 + k0 + (q ^ (r & 7))*8, lA + s*8);
        }
        #pragma unroll
        for (int it = 0; it < 2; ++it){
            int s = tid + it*256;
            int r = s >> 3, q = s & 7;
            gload_lds16(BT + (size_t)(rowB0 + r)*1024 + k0 + (q ^ (r & 7))*8, lB + s*8);
        }
        __syncthreads();
        #pragma unroll
        for (int kh = 0; kh < 2; kh++){
            bf16x8 af[2], bfr[4];
            int qb = kh*4 + kg;
            int qp = (qb ^ swz) * 8;
            #pragma unroll
            for (int mt = 0; mt < 2; mt++) af[mt]  = *(const bf16x8*)(lA + (wm + mt*16 + lm)*64 + qp);
            #pragma unroll
            for (int nt = 0; nt < 4; nt++) bfr[nt] = *(const bf16x8*)(lB + (nt*16 + lm)*64 + qp);
            #pragma unroll
            for (int mt = 0; mt < 2; mt++)
                #pragma unroll
                for (int nt = 0; nt < 4; nt++)
                    acc[mt][nt] = __builtin_amdgcn_mfma_f32_16x16x32_bf16(af[mt], bfr[nt], acc[mt][nt], 0, 0, 0);
        }
        __syncthreads();
    }
    #pragma unroll
    for (int mt = 0; mt < 2; mt++){
        int row_base = bm*128 + wm + mt*16 + kg*4;
        #pragma unroll
        for (int nt = 0; nt < 4; nt++){
            int col = bn*64 + nt*16 + lm;
            #pragma unroll
            for (int r = 0; r < 4; r++){
                int row = row_base + r;
                if (row < N_NODES) C[(size_t)row*HT + col] = f2bf(acc[mt][nt][r]);
            }
        }
    }
    /* partial attention dots over this block's 64 cols (head = bn>>1) */
    int head = bn >> 1;
    float as_l[4], ad_l[4];
    #pragma unroll
    for (int nt = 0; nt < 4; nt++){
        as_l[nt] = aS[bn*64 + nt*16 + lm];
        ad_l[nt] = aD[bn*64 + nt*16 + lm];
    }
    #pragma unroll
    for (int mt = 0; mt < 2; mt++){
        #pragma unroll
        for (int r = 0; r < 4; r++){
            float ps = acc[mt][0][r]*as_l[0] + acc[mt][1][r]*as_l[1]
                     + acc[mt][2][r]*as_l[2] + acc[mt][3][r]*as_l[3];
            float pd = acc[mt][0][r]*ad_l[0] + acc[mt][1][r]*ad_l[1]
                     + acc[mt][2][r]*ad_l[2] + acc[mt][3][r]*ad_l[3];
            #pragma unroll
            for (int o = 1; o < 16; o <<= 1){ ps += __shfl_xor(ps, o, 64); pd += __shfl_xor(pd, o, 64); }
            if (lm == 0){
                int row = bm*128 + wm + mt*16 + kg*4 + r;
                if (row < N_NODES){
                    atomicAdd(&alS2[row*HEADS + head], ps);
                    atomicAdd(&alD2[row*HEADS + head], pd);
                }
            }
        }
    }
}

/* ---------------- layer-3 GEMM: wave-per-node, W3 in registers ---------------- */
__global__ __launch_bounds__(256) void k_gemm3(const ushort_t* __restrict__ A, const float* __restrict__ W3,
                                               const float* __restrict__ s3,
                                               float* __restrict__ h3, float* __restrict__ al3s, float* __restrict__ al3d){
    int tid = threadIdx.x;
    int lane = tid & 63, wave = tid >> 6;
    int n = blockIdx.x * 4 + wave;
    if (n >= N_NODES) return;
    float4 w3r[16];
    #pragma unroll
    for (int j = 0; j < 16; j++) w3r[j] = ((const float4*)W3)[lane*16 + j];
    const uint4* ap = (const uint4*)(A + (size_t)n*HT + lane*16);
    uint4 u0 = ap[0], u1 = ap[1];
    uint32 uu[8] = {u0.x,u0.y,u0.z,u0.w,u1.x,u1.y,u1.z,u1.w};
    float acc0=0.f, acc1=0.f, acc2=0.f, acc3=0.f;
    #pragma unroll
    for (int p = 0; p < 8; p++){
        float lo, hi;
        unpack2(uu[p], lo, hi);
        float4 wl = w3r[p*2], wh = w3r[p*2+1];
        acc0 += lo*wl.x + hi*wh.x;
        acc1 += lo*wl.y + hi*wh.y;
        acc2 += lo*wl.z + hi*wh.z;
        acc3 += lo*wl.w + hi*wh.w;
    }
    #pragma unroll
    for (int o = 32; o; o >>= 1){
        acc0 += __shfl_xor(acc0, o, 64); acc1 += __shfl_xor(acc1, o, 64);
        acc2 += __shfl_xor(acc2, o, 64); acc3 += __shfl_xor(acc3, o, 64);
    }
    if (lane == 0){
        *(float4*)(h3 + n*4) = make_float4(acc0, acc1, acc2, acc3);
        al3s[n] = acc0*s3[0] + acc1*s3[1] + acc2*s3[2] + acc3*s3[3];
        al3d[n] = acc0*s3[16] + acc1*s3[17] + acc2*s3[18] + acc3*s3[19];
    }
}

/* ---------------- layer-3 attention aggregate: wave-per-node ---------------- */
__global__ __launch_bounds__(256) void k_gat_agg3(const float* __restrict__ h3, const float* __restrict__ al3s,
                                                  const float* __restrict__ al3d, const int* __restrict__ offs,
                                                  const int* __restrict__ srcs, const float* __restrict__ b3,
                                                  const int* __restrict__ flags, void* __restrict__ out){
    int tid = threadIdx.x;
    int l = tid & 63, wave = tid >> 6;
    int n = blockIdx.x * 4 + wave;
    if (n >= N_NODES) return;
    int beg = offs[n], end = offs[n+1];
    float ad = al3d[n];
    float m = -1e30f;
    for (int e = beg + l; e < end; e += 64){
        float v = al3s[srcs[e]] + ad; v = v > 0.f ? v : NEG*v;
        m = fmaxf(m, v);
    }
    #pragma unroll
    for (int o = 32; o; o >>= 1) m = fmaxf(m, __shfl_xor(m, o, 64));
    float z = 0.f;
    for (int e = beg + l; e < end; e += 64){
        float v = al3s[srcs[e]] + ad; v = v > 0.f ? v : NEG*v;
        z += __expf(v - m);
    }
    #pragma unroll
    for (int o = 32; o; o >>= 1) z += __shfl_xor(z, o, 64);
    float inv = 1.f / (z + 1e-16f);
    float a0=0.f, a1=0.f, a2=0.f, a3=0.f;
    for (int e = beg + l; e < end; e += 64){
        int s = srcs[e];
        float v = al3s[s] + ad; v = v > 0.f ? v : NEG*v;
        float w = __expf(v - m) * inv;
        float4 hv = *(const float4*)(h3 + s*4);
        a0 += w*hv.x; a1 += w*hv.y; a2 += w*hv.z; a3 += w*hv.w;
    }
    #pragma unroll
    for (int o = 32; o; o >>= 1){
        a0 += __shfl_xor(a0, o, 64); a1 += __shfl_xor(a1, o, 64);
        a2 += __shfl_xor(a2, o, 64); a3 += __shfl_xor(a3, o, 64);
    }
    if (l == 0){
        float r0 = fmaxf(a0 + b3[0], 0.f);
        float r1 = fmaxf(a1 + b3[1], 0.f);
        float r2 = fmaxf(a2 + b3[2], 0.f);
        float r3 = fmaxf(a3 + b3[3], 0.f);
        if (flags[1]){
            float* o4 = (float*)out;
            o4[n*4+0]=r0; o4[n*4+1]=r1; o4[n*4+2]=r2; o4[n*4+3]=r3;
        } else {
            ushort_t* o2 = (ushort_t*)out;
            o2[n*4+0]=f2bf(r0); o2[n*4+1]=f2bf(r1); o2[n*4+2]=f2bf(r2); o2[n*4+3]=f2bf(r3);
        }
    }
}

extern "C" void kernel_launch(void* const* d_in, const int* in_sizes, int n_in,
                              void* d_out, int out_size, void* d_ws, size_t ws_size,
                              hipStream_t stream){
    const void* x   = d_in[0];
    const void* ei  = d_in[1];
    const void* W1  = d_in[2];
    const void* W2  = d_in[6];
    const void* W3  = d_in[10];

    char* ws = (char*)d_ws;
    int* flags     = (int*)(ws + O_FLAG);
    uint32* bnd    = (uint32*)(ws + O_BND);
    int* bsum      = (int*)(ws + O_BSUM);
    int* counts    = (int*)(ws + O_COUNTS);   /* also cursors */
    int* offs      = (int*)(ws + O_OFFS);
    int* ssort     = (int*)(ws + O_SSORT);
    float* alS1    = (float*)(ws + O_ALS1);
    float* alD1    = (float*)(ws + O_ALD1);
    float* alS2    = (float*)(ws + O_ALS2);
    float* alD2    = (float*)(ws + O_ALD2);
    float* al3s    = (float*)(ws + O_AL3S);
    float* al3d    = (float*)(ws + O_AL3D);
    float* h3      = (float*)(ws + O_H3);
    float* wvecF   = (float*)(ws + O_WVEC);
    float* W3F     = (float*)(ws + O_W3F);
    float* s3F     = (float*)(ws + O_S3F);
    ushort_t* W2T  = (ushort_t*)(ws + O_W2T);
    ushort_t* bufA = (ushort_t*)(ws + O_BUFA);
    ushort_t* bufB = (ushort_t*)(ws + O_BUFB);

    const int EB = (ET + 255) / 256;

    CvtArgs ca;
    ca.vsrc[0]=d_in[3];  ca.vsrc[1]=d_in[4];  ca.vsrc[2]=d_in[5];
    ca.vsrc[3]=d_in[7];  ca.vsrc[4]=d_in[8];  ca.vsrc[5]=d_in[9];
    ca.w3src = W3;
    ca.s3src[0]=d_in[11]; ca.s3src[1]=d_in[12]; ca.s3src[2]=d_in[13];

    k_pre<<<12, 256, 0, stream>>>(ca, (const uint32*)W1, (const int*)ei, flags,
                                  wvecF, W3F, s3F, counts, bnd);
    /* extract/hist ∥ gemm1+dots ∥ W2 transpose ∥ alS2/alD2 zero */
    k_mega1<<<1846, 256, 0, stream>>>(ei, x, W1, W2, flags, wvecF, counts,
                                      bufA, alS1, alD1, bnd, W2T, alS2, alD2);
    k_scan_a<<<40, 256, 0, stream>>>(counts, bsum);
    k_scan_b<<<40, 256, 0, stream>>>(counts, bsum, offs);
    k_scatter<<<EB, 256, 0, stream>>>(ei, flags, counts, ssort);

    /* layer 1 aggregate */
    k_gat_agg<<<5000, 256, 0, stream>>>(bufA, alS1, alD1, bnd, 0, offs, ssort, wvecF + 2*1024, bufB);

    /* layer 2 */
    k_gemm2<<<dim3(16, 79), 256, 0, stream>>>(bufB, W2T, bufA, wvecF + 3*1024, wvecF + 4*1024, alS2, alD2);
    k_bound<<<40, 256, 0, stream>>>(alS2, alD2, bnd);
    k_gat_agg<<<5000, 256, 0, stream>>>(bufA, alS2, alD2, bnd, 16, offs, ssort, wvecF + 5*1024, bufB);

    /* layer 3 */
    k_gemm3<<<2500, 256, 0, stream>>>(bufB, W3F, s3F, h3, al3s, al3d);
    k_gat_agg3<<<2500, 256, 0, stream>>>(h3, al3s, al3d, offs, ssort, s3F + 32, flags, d_out);
}